// Round 1
// baseline (717.023 us; speedup 1.0000x reference)
//
#include <hip/hip_runtime.h>

// GCN: 3x (h@W -> gather-aggregate via CSR-by-dest + self-loop + bias [-> ReLU])
// Outputs: concat(x, h1, h2, h3), each [N,64] fp32.
// CSR via 2-level counting sort; deg/dinv fused into pass 2; gather unrolled x4 for MLP.
// R1: k_gemm64 rewritten as 128-row block, 8x4 register tile, b128 LDS reads,
//     XOR-swizzled A staging (was 5 scalar LDS reads per 4 FMAs -> LDS-pipe-bound).

#define TPB 256
#define P1_CHUNK 8192   // edges per block in pass0/pass1
#define DSH 7           // coarse bucket = dest >> DSH (128 dests/bucket)
#define DNB 128         // dests per bucket
#define STAGE_CAP 4096  // pass-2 LDS staging capacity (edges)

// ---- Pass 0: coarse histogram (per-block LDS hist, merged with few global atomics)
__global__ __launch_bounds__(TPB) void k_p0(const int* __restrict__ col,
                                            int* __restrict__ chist, int E, int nbk) {
    __shared__ int h[1024];
    int tid = threadIdx.x;
    for (int i = tid; i < nbk; i += TPB) h[i] = 0;
    __syncthreads();
    int s0 = blockIdx.x * P1_CHUNK;
    int s1 = min(s0 + P1_CHUNK, E);
    for (int i = s0 + tid; i < s1; i += TPB) atomicAdd(&h[col[i] >> DSH], 1);
    __syncthreads();
    for (int i = tid; i < nbk; i += TPB)
        if (h[i]) atomicAdd(&chist[i], h[i]);
}

// ---- Scan coarse buckets (single block), init cursor copy.
__global__ __launch_bounds__(1024) void k_scanb(const int* __restrict__ chist,
                                                int* __restrict__ cbase,
                                                int* __restrict__ ccur, int nbk, int E) {
    __shared__ int s[1024];
    int tid = threadIdx.x;
    int v = (tid < nbk) ? chist[tid] : 0;
    s[tid] = v;
    __syncthreads();
    for (int off = 1; off < 1024; off <<= 1) {
        int t = (tid >= off) ? s[tid - off] : 0;
        __syncthreads();
        s[tid] += t;
        __syncthreads();
    }
    if (tid < nbk) { int ex = s[tid] - v; cbase[tid] = ex; ccur[tid] = ex; }
    if (tid == 0) cbase[nbk] = E;
}

// ---- Pass 1: scatter edges into coarse-bucket runs (one global atomic per block-bucket).
// Packs (src | destlo<<20, w) so pass 2 doesn't need col[].
__global__ __launch_bounds__(TPB) void k_p1(const int* __restrict__ row,
                                            const int* __restrict__ col,
                                            const float* __restrict__ w,
                                            int* __restrict__ ccur,
                                            int2* __restrict__ bkt, int E, int nbk) {
    __shared__ int h[1024];
    __shared__ int base[1024];
    int tid = threadIdx.x;
    for (int i = tid; i < nbk; i += TPB) h[i] = 0;
    __syncthreads();
    int s0 = blockIdx.x * P1_CHUNK;
    int s1 = min(s0 + P1_CHUNK, E);
    for (int i = s0 + tid; i < s1; i += TPB) atomicAdd(&h[col[i] >> DSH], 1);
    __syncthreads();
    for (int i = tid; i < nbk; i += TPB) {
        int c = h[i];
        base[i] = c ? atomicAdd(&ccur[i], c) : 0;
        h[i] = 0;
    }
    __syncthreads();
    for (int i = s0 + tid; i < s1; i += TPB) {
        int c = col[i];
        int b = c >> DSH;
        int r = atomicAdd(&h[b], 1);
        bkt[base[b] + r] = make_int2(row[i] | ((c & (DNB - 1)) << 20), __float_as_int(w[i]));
    }
}

// ---- Pass 2: fine sort within bucket (LDS), write starts + edges coalesced,
//      and compute deg/dinv per dest (its edges are all here).
__global__ __launch_bounds__(TPB) void k_p2(const int2* __restrict__ bkt,
                                            const int* __restrict__ cbase,
                                            int* __restrict__ starts,
                                            int2* __restrict__ edges,
                                            float* __restrict__ dinv, int n, int E) {
    __shared__ int hist[DNB];
    __shared__ int curs[DNB];
    __shared__ int sc[DNB];
    __shared__ int2 stage[STAGE_CAP];
    int tid = threadIdx.x;
    int b = blockIdx.x;
    int s0 = cbase[b], s1 = cbase[b + 1];
    int cnt = s1 - s0;
    int nodeBase = b << DSH;
    if (tid < DNB) hist[tid] = 0;
    __syncthreads();
    for (int i = s0 + tid; i < s1; i += TPB)
        atomicAdd(&hist[(unsigned)bkt[i].x >> 20], 1);
    __syncthreads();
    int v = 0;
    if (tid < DNB) { v = hist[tid]; sc[tid] = v; }
    __syncthreads();
    for (int off = 1; off < DNB; off <<= 1) {
        int t = 0;
        if (tid < DNB && tid >= off) t = sc[tid - off];
        __syncthreads();
        if (tid < DNB) sc[tid] += t;
        __syncthreads();
    }
    if (tid < DNB) {
        int ex = sc[tid] - v;
        curs[tid] = ex;
        int node = nodeBase + tid;
        if (node < n) starts[node] = s0 + ex;
    }
    if (b == 0 && tid == 0) starts[n] = E;
    __syncthreads();
    if (cnt <= STAGE_CAP) {
        for (int i = s0 + tid; i < s1; i += TPB) {
            int2 ed = bkt[i];
            int d = (unsigned)ed.x >> 20;
            int r = atomicAdd(&curs[d], 1);
            stage[r] = make_int2(ed.x & 0xFFFFF, ed.y);
        }
        __syncthreads();
        for (int i = tid; i < cnt; i += TPB) edges[s0 + i] = stage[i];
        // deg/dinv from LDS stage: node tid's run = [sc[tid]-v, sc[tid])
        if (tid < DNB) {
            int node = nodeBase + tid;
            if (node < n) {
                float d = 1.0f;  // self-loop
                for (int j = sc[tid] - v; j < sc[tid]; ++j)
                    d += __int_as_float(stage[j].y);
                dinv[node] = rsqrtf(d);
            }
        }
    } else {  // overflow fallback: direct (uncoalesced but correct)
        for (int i = s0 + tid; i < s1; i += TPB) {
            int2 ed = bkt[i];
            int d = (unsigned)ed.x >> 20;
            int r = atomicAdd(&curs[d], 1);
            edges[s0 + r] = make_int2(ed.x & 0xFFFFF, ed.y);
        }
        __syncthreads();
        if (tid < DNB) {
            int node = nodeBase + tid;
            if (node < n) {
                float d = 1.0f;
                for (int j = sc[tid] - v; j < sc[tid]; ++j)
                    d += __int_as_float(edges[s0 + j].y);
                dinv[node] = rsqrtf(d);
            }
        }
    }
}

// ---- in-place w -> norm (dinv[src]*w*dinv[dest])
__global__ __launch_bounds__(TPB) void k_normcsr(const int* __restrict__ starts,
                                                 const float* __restrict__ dinv,
                                                 int2* __restrict__ edges, int n) {
    int i = blockIdx.x * TPB + threadIdx.x;
    if (i >= n) return;
    int s0 = starts[i], s1 = starts[i + 1];
    float dn = dinv[i];
    for (int s = s0; s < s1; ++s) {
        int2 ed = edges[s];
        edges[s].y = __float_as_int(dinv[ed.x] * __int_as_float(ed.y) * dn);
    }
}

// ---- out[N,64] = in[N,64] @ W[64,64].
// 128 rows/block, 256 threads; thread tile = 8 rows x 4 cols (32 acc VGPRs).
// All LDS accesses are b128. A staged with XOR swizzle (c4 ^= (row>>3)&3) so the
// four rg-distinct broadcast reads hit distinct bank slots (rg stride 2048B would
// otherwise alias mod 128B -> 4-way conflict).
__global__ __launch_bounds__(TPB) void k_gemm64(const float* __restrict__ in,
                                                const float* __restrict__ Wg,
                                                float* __restrict__ out, int n) {
    __shared__ float4 Ws[1024];   // [64 k][16 j4]
    __shared__ float4 As[2048];   // [128 r][16 c4], swizzled
    int tid = threadIdx.x;
    const float4* Wf4 = (const float4*)Wg;
    #pragma unroll
    for (int i = 0; i < 4; ++i) Ws[i * 256 + tid] = Wf4[i * 256 + tid];
    int rowbase = blockIdx.x * 128;
    const float4* Af4 = (const float4*)in;
    #pragma unroll
    for (int i = 0; i < 8; ++i) {
        int f4 = i * 256 + tid;
        int r = f4 >> 4, c4 = f4 & 15;
        float4 v = make_float4(0.f, 0.f, 0.f, 0.f);
        if (rowbase + r < n) v = Af4[(size_t)(rowbase + r) * 16 + c4];
        As[r * 16 + (c4 ^ ((r >> 3) & 3))] = v;
    }
    __syncthreads();
    int jg = tid & 15;       // output col group (4 cols)
    int rg = tid >> 4;       // row group (8 rows)
    int r0 = rg * 8;
    int sw = rg & 3;         // swizzle key for this thread's rows
    float4 acc[8];
    #pragma unroll
    for (int rr = 0; rr < 8; ++rr) acc[rr] = make_float4(0.f, 0.f, 0.f, 0.f);
    #pragma unroll
    for (int kt = 0; kt < 16; ++kt) {
        float4 w0 = Ws[(kt * 4 + 0) * 16 + jg];
        float4 w1 = Ws[(kt * 4 + 1) * 16 + jg];
        float4 w2 = Ws[(kt * 4 + 2) * 16 + jg];
        float4 w3 = Ws[(kt * 4 + 3) * 16 + jg];
        int ac = kt ^ sw;
        #pragma unroll
        for (int rr = 0; rr < 8; ++rr) {
            float4 a = As[(r0 + rr) * 16 + ac];
            acc[rr].x = fmaf(a.x, w0.x, acc[rr].x);
            acc[rr].y = fmaf(a.x, w0.y, acc[rr].y);
            acc[rr].z = fmaf(a.x, w0.z, acc[rr].z);
            acc[rr].w = fmaf(a.x, w0.w, acc[rr].w);
            acc[rr].x = fmaf(a.y, w1.x, acc[rr].x);
            acc[rr].y = fmaf(a.y, w1.y, acc[rr].y);
            acc[rr].z = fmaf(a.y, w1.z, acc[rr].z);
            acc[rr].w = fmaf(a.y, w1.w, acc[rr].w);
            acc[rr].x = fmaf(a.z, w2.x, acc[rr].x);
            acc[rr].y = fmaf(a.z, w2.y, acc[rr].y);
            acc[rr].z = fmaf(a.z, w2.z, acc[rr].z);
            acc[rr].w = fmaf(a.z, w2.w, acc[rr].w);
            acc[rr].x = fmaf(a.w, w3.x, acc[rr].x);
            acc[rr].y = fmaf(a.w, w3.y, acc[rr].y);
            acc[rr].z = fmaf(a.w, w3.z, acc[rr].z);
            acc[rr].w = fmaf(a.w, w3.w, acc[rr].w);
        }
    }
    #pragma unroll
    for (int rr = 0; rr < 8; ++rr) {
        int r = rowbase + r0 + rr;
        if (r < n) *(float4*)&out[(size_t)r * 64 + jg * 4] = acc[rr];
    }
}

// ---- gather-aggregate, unrolled x4 for memory-level parallelism.
__global__ __launch_bounds__(TPB) void k_gather(const int* __restrict__ starts,
                                                const int2* __restrict__ edges,
                                                const float* __restrict__ hw,
                                                const float* __restrict__ dinv,
                                                const float* __restrict__ b,
                                                float* __restrict__ out,
                                                int n, int relu) {
    int idx = blockIdx.x * TPB + threadIdx.x;
    int node = idx >> 4;
    if (node >= n) return;
    int f = (idx & 15) << 2;
    int s0 = starts[node], s1 = starts[node + 1];
    float di = dinv[node];
    float sc = di * di;
    float4 hself = *(const float4*)&hw[(size_t)node * 64 + f];
    float4 bb = *(const float4*)&b[f];
    float4 acc;
    acc.x = fmaf(hself.x, sc, bb.x);
    acc.y = fmaf(hself.y, sc, bb.y);
    acc.z = fmaf(hself.z, sc, bb.z);
    acc.w = fmaf(hself.w, sc, bb.w);
    int e = s0;
    for (; e + 4 <= s1; e += 4) {
        int2 e0 = edges[e + 0];
        int2 e1 = edges[e + 1];
        int2 e2 = edges[e + 2];
        int2 e3 = edges[e + 3];
        float4 h0 = *(const float4*)&hw[(size_t)e0.x * 64 + f];
        float4 h1 = *(const float4*)&hw[(size_t)e1.x * 64 + f];
        float4 h2 = *(const float4*)&hw[(size_t)e2.x * 64 + f];
        float4 h3 = *(const float4*)&hw[(size_t)e3.x * 64 + f];
        float n0 = __int_as_float(e0.y), n1 = __int_as_float(e1.y);
        float n2 = __int_as_float(e2.y), n3 = __int_as_float(e3.y);
        acc.x = fmaf(h0.x, n0, acc.x); acc.y = fmaf(h0.y, n0, acc.y);
        acc.z = fmaf(h0.z, n0, acc.z); acc.w = fmaf(h0.w, n0, acc.w);
        acc.x = fmaf(h1.x, n1, acc.x); acc.y = fmaf(h1.y, n1, acc.y);
        acc.z = fmaf(h1.z, n1, acc.z); acc.w = fmaf(h1.w, n1, acc.w);
        acc.x = fmaf(h2.x, n2, acc.x); acc.y = fmaf(h2.y, n2, acc.y);
        acc.z = fmaf(h2.z, n2, acc.z); acc.w = fmaf(h2.w, n2, acc.w);
        acc.x = fmaf(h3.x, n3, acc.x); acc.y = fmaf(h3.y, n3, acc.y);
        acc.z = fmaf(h3.z, n3, acc.z); acc.w = fmaf(h3.w, n3, acc.w);
    }
    for (; e < s1; ++e) {
        int2 ed = edges[e];
        float nm = __int_as_float(ed.y);
        float4 h = *(const float4*)&hw[(size_t)ed.x * 64 + f];
        acc.x = fmaf(h.x, nm, acc.x);
        acc.y = fmaf(h.y, nm, acc.y);
        acc.z = fmaf(h.z, nm, acc.z);
        acc.w = fmaf(h.w, nm, acc.w);
    }
    if (relu) {
        acc.x = acc.x > 0.f ? acc.x : 0.f;
        acc.y = acc.y > 0.f ? acc.y : 0.f;
        acc.z = acc.z > 0.f ? acc.z : 0.f;
        acc.w = acc.w > 0.f ? acc.w : 0.f;
    }
    *(float4*)&out[(size_t)node * 64 + f] = acc;
}

extern "C" void kernel_launch(void* const* d_in, const int* in_sizes, int n_in,
                              void* d_out, int out_size, void* d_ws, size_t ws_size,
                              hipStream_t stream) {
    const float* x = (const float*)d_in[0];
    const int* ei = (const int*)d_in[1];      // int32 on device
    const float* ew = (const float*)d_in[2];
    const float* Wl[3] = {(const float*)d_in[3], (const float*)d_in[5], (const float*)d_in[7]};
    const float* Bl[3] = {(const float*)d_in[4], (const float*)d_in[6], (const float*)d_in[8]};

    const int n = in_sizes[0] / 64;
    const int E = in_sizes[2];
    const int* row = ei;       // edge_index[0]
    const int* col = ei + E;   // edge_index[1]
    float* out = (float*)d_out;

    const int nbk = (n + DNB - 1) >> DSH;                 // coarse buckets (<=1024 for n<=131072)
    const int p1b = (E + P1_CHUNK - 1) / P1_CHUNK;

    // workspace layout (256B aligned):
    // dinv[n] | hw[n*64] (bkt int2[E] aliased inside; hw written only after pass 2)
    // | starts[n+1] | chist[1024] | cbase[1025] | ccur[1024] | edges[E] int2
    char* ws = (char*)d_ws;
    size_t o = 0;
    float* dinv  = (float*)(ws + o);  o = (o + (size_t)n * 4 + 255) & ~(size_t)255;
    float* hw    = (float*)(ws + o);
    int2*  bkt   = (int2*)(ws + o);   o = (o + (size_t)n * 256 + 255) & ~(size_t)255;
    int* starts  = (int*)(ws + o);    o = (o + (size_t)(n + 1) * 4 + 255) & ~(size_t)255;
    int* chist   = (int*)(ws + o);    o = (o + 1024 * 4 + 255) & ~(size_t)255;
    int* cbase   = (int*)(ws + o);    o = (o + 1025 * 4 + 255) & ~(size_t)255;
    int* ccur    = (int*)(ws + o);    o = (o + 1024 * 4 + 255) & ~(size_t)255;
    int2* edges  = (int2*)(ws + o);

    // output 0 = x
    hipMemcpyAsync(out, x, (size_t)n * 64 * sizeof(float), hipMemcpyDeviceToDevice, stream);

    // CSR by destination: 2-level counting sort (+ fused deg/dinv in pass 2)
    hipMemsetAsync(chist, 0, (size_t)nbk * 4, stream);
    k_p0<<<p1b, TPB, 0, stream>>>(col, chist, E, nbk);
    k_scanb<<<1, 1024, 0, stream>>>(chist, cbase, ccur, nbk, E);
    k_p1<<<p1b, TPB, 0, stream>>>(row, col, ew, ccur, bkt, E, nbk);
    k_p2<<<nbk, TPB, 0, stream>>>(bkt, cbase, starts, edges, dinv, n, E);
    k_normcsr<<<(n + TPB - 1) / TPB, TPB, 0, stream>>>(starts, dinv, edges, n);

    const float* hin = x;
    for (int L = 0; L < 3; ++L) {
        float* oseg = out + (size_t)(L + 1) * n * 64;
        k_gemm64<<<(n + 127) / 128, TPB, 0, stream>>>(hin, Wl[L], hw, n);
        k_gather<<<(n * 16 + TPB - 1) / TPB, TPB, 0, stream>>>(starts, edges, hw, dinv, Bl[L], oseg, n, L < 2 ? 1 : 0);
        hin = oseg;
    }
}

// Round 2
// 438.709 us; speedup vs baseline: 1.6344x; 1.6344x over previous
//
#include <hip/hip_runtime.h>

// GCN: 3x (h@W -> gather-aggregate via CSR-by-dest + self-loop + bias [-> ReLU])
// Outputs: concat(x, h1, h2, h3), each [N,64] fp32.
// CSR via 2-level counting sort; deg/dinv fused into pass 2; gather unrolled x4 for MLP.
// R1: k_gemm64 128-row block, 8x4 register tile, b128 LDS, XOR-swizzled A staging.
// R2: fix R1 spill regression: #pragma unroll 2 on kt loop (full unroll hoisted 64
//     float4 of W -> 256 VGPRs -> scratch spill, FETCH/WRITE 4-8x inflated) and
//     __launch_bounds__(TPB,3) to cap allocator at the LDS-limited occupancy.

#define TPB 256
#define P1_CHUNK 8192   // edges per block in pass0/pass1
#define DSH 7           // coarse bucket = dest >> DSH (128 dests/bucket)
#define DNB 128         // dests per bucket
#define STAGE_CAP 4096  // pass-2 LDS staging capacity (edges)

// ---- Pass 0: coarse histogram (per-block LDS hist, merged with few global atomics)
__global__ __launch_bounds__(TPB) void k_p0(const int* __restrict__ col,
                                            int* __restrict__ chist, int E, int nbk) {
    __shared__ int h[1024];
    int tid = threadIdx.x;
    for (int i = tid; i < nbk; i += TPB) h[i] = 0;
    __syncthreads();
    int s0 = blockIdx.x * P1_CHUNK;
    int s1 = min(s0 + P1_CHUNK, E);
    for (int i = s0 + tid; i < s1; i += TPB) atomicAdd(&h[col[i] >> DSH], 1);
    __syncthreads();
    for (int i = tid; i < nbk; i += TPB)
        if (h[i]) atomicAdd(&chist[i], h[i]);
}

// ---- Scan coarse buckets (single block), init cursor copy.
__global__ __launch_bounds__(1024) void k_scanb(const int* __restrict__ chist,
                                                int* __restrict__ cbase,
                                                int* __restrict__ ccur, int nbk, int E) {
    __shared__ int s[1024];
    int tid = threadIdx.x;
    int v = (tid < nbk) ? chist[tid] : 0;
    s[tid] = v;
    __syncthreads();
    for (int off = 1; off < 1024; off <<= 1) {
        int t = (tid >= off) ? s[tid - off] : 0;
        __syncthreads();
        s[tid] += t;
        __syncthreads();
    }
    if (tid < nbk) { int ex = s[tid] - v; cbase[tid] = ex; ccur[tid] = ex; }
    if (tid == 0) cbase[nbk] = E;
}

// ---- Pass 1: scatter edges into coarse-bucket runs (one global atomic per block-bucket).
// Packs (src | destlo<<20, w) so pass 2 doesn't need col[].
__global__ __launch_bounds__(TPB) void k_p1(const int* __restrict__ row,
                                            const int* __restrict__ col,
                                            const float* __restrict__ w,
                                            int* __restrict__ ccur,
                                            int2* __restrict__ bkt, int E, int nbk) {
    __shared__ int h[1024];
    __shared__ int base[1024];
    int tid = threadIdx.x;
    for (int i = tid; i < nbk; i += TPB) h[i] = 0;
    __syncthreads();
    int s0 = blockIdx.x * P1_CHUNK;
    int s1 = min(s0 + P1_CHUNK, E);
    for (int i = s0 + tid; i < s1; i += TPB) atomicAdd(&h[col[i] >> DSH], 1);
    __syncthreads();
    for (int i = tid; i < nbk; i += TPB) {
        int c = h[i];
        base[i] = c ? atomicAdd(&ccur[i], c) : 0;
        h[i] = 0;
    }
    __syncthreads();
    for (int i = s0 + tid; i < s1; i += TPB) {
        int c = col[i];
        int b = c >> DSH;
        int r = atomicAdd(&h[b], 1);
        bkt[base[b] + r] = make_int2(row[i] | ((c & (DNB - 1)) << 20), __float_as_int(w[i]));
    }
}

// ---- Pass 2: fine sort within bucket (LDS), write starts + edges coalesced,
//      and compute deg/dinv per dest (its edges are all here).
__global__ __launch_bounds__(TPB) void k_p2(const int2* __restrict__ bkt,
                                            const int* __restrict__ cbase,
                                            int* __restrict__ starts,
                                            int2* __restrict__ edges,
                                            float* __restrict__ dinv, int n, int E) {
    __shared__ int hist[DNB];
    __shared__ int curs[DNB];
    __shared__ int sc[DNB];
    __shared__ int2 stage[STAGE_CAP];
    int tid = threadIdx.x;
    int b = blockIdx.x;
    int s0 = cbase[b], s1 = cbase[b + 1];
    int cnt = s1 - s0;
    int nodeBase = b << DSH;
    if (tid < DNB) hist[tid] = 0;
    __syncthreads();
    for (int i = s0 + tid; i < s1; i += TPB)
        atomicAdd(&hist[(unsigned)bkt[i].x >> 20], 1);
    __syncthreads();
    int v = 0;
    if (tid < DNB) { v = hist[tid]; sc[tid] = v; }
    __syncthreads();
    for (int off = 1; off < DNB; off <<= 1) {
        int t = 0;
        if (tid < DNB && tid >= off) t = sc[tid - off];
        __syncthreads();
        if (tid < DNB) sc[tid] += t;
        __syncthreads();
    }
    if (tid < DNB) {
        int ex = sc[tid] - v;
        curs[tid] = ex;
        int node = nodeBase + tid;
        if (node < n) starts[node] = s0 + ex;
    }
    if (b == 0 && tid == 0) starts[n] = E;
    __syncthreads();
    if (cnt <= STAGE_CAP) {
        for (int i = s0 + tid; i < s1; i += TPB) {
            int2 ed = bkt[i];
            int d = (unsigned)ed.x >> 20;
            int r = atomicAdd(&curs[d], 1);
            stage[r] = make_int2(ed.x & 0xFFFFF, ed.y);
        }
        __syncthreads();
        for (int i = tid; i < cnt; i += TPB) edges[s0 + i] = stage[i];
        // deg/dinv from LDS stage: node tid's run = [sc[tid]-v, sc[tid])
        if (tid < DNB) {
            int node = nodeBase + tid;
            if (node < n) {
                float d = 1.0f;  // self-loop
                for (int j = sc[tid] - v; j < sc[tid]; ++j)
                    d += __int_as_float(stage[j].y);
                dinv[node] = rsqrtf(d);
            }
        }
    } else {  // overflow fallback: direct (uncoalesced but correct)
        for (int i = s0 + tid; i < s1; i += TPB) {
            int2 ed = bkt[i];
            int d = (unsigned)ed.x >> 20;
            int r = atomicAdd(&curs[d], 1);
            edges[s0 + r] = make_int2(ed.x & 0xFFFFF, ed.y);
        }
        __syncthreads();
        if (tid < DNB) {
            int node = nodeBase + tid;
            if (node < n) {
                float d = 1.0f;
                for (int j = sc[tid] - v; j < sc[tid]; ++j)
                    d += __int_as_float(edges[s0 + j].y);
                dinv[node] = rsqrtf(d);
            }
        }
    }
}

// ---- in-place w -> norm (dinv[src]*w*dinv[dest])
__global__ __launch_bounds__(TPB) void k_normcsr(const int* __restrict__ starts,
                                                 const float* __restrict__ dinv,
                                                 int2* __restrict__ edges, int n) {
    int i = blockIdx.x * TPB + threadIdx.x;
    if (i >= n) return;
    int s0 = starts[i], s1 = starts[i + 1];
    float dn = dinv[i];
    for (int s = s0; s < s1; ++s) {
        int2 ed = edges[s];
        edges[s].y = __float_as_int(dinv[ed.x] * __int_as_float(ed.y) * dn);
    }
}

// ---- out[N,64] = in[N,64] @ W[64,64].
// 128 rows/block, 256 threads; thread tile = 8 rows x 4 cols (32 acc VGPRs).
// All LDS accesses are b128. A staged with XOR swizzle (c4 ^= (row>>3)&3) so the
// four rg-distinct broadcast reads hit distinct bank slots.
// unroll 2 (NOT full): full unroll hoists 64 float4 of W -> 256 VGPRs -> spill.
// launch_bounds(TPB,3): LDS (48KB) caps occupancy at 3 blocks/CU anyway; cap the
// register allocator to match (~168 VGPRs) so it never spills.
__global__ __launch_bounds__(TPB, 3) void k_gemm64(const float* __restrict__ in,
                                                   const float* __restrict__ Wg,
                                                   float* __restrict__ out, int n) {
    __shared__ float4 Ws[1024];   // [64 k][16 j4]
    __shared__ float4 As[2048];   // [128 r][16 c4], swizzled
    int tid = threadIdx.x;
    const float4* Wf4 = (const float4*)Wg;
    #pragma unroll
    for (int i = 0; i < 4; ++i) Ws[i * 256 + tid] = Wf4[i * 256 + tid];
    int rowbase = blockIdx.x * 128;
    const float4* Af4 = (const float4*)in;
    #pragma unroll
    for (int i = 0; i < 8; ++i) {
        int f4 = i * 256 + tid;
        int r = f4 >> 4, c4 = f4 & 15;
        float4 v = make_float4(0.f, 0.f, 0.f, 0.f);
        if (rowbase + r < n) v = Af4[(size_t)(rowbase + r) * 16 + c4];
        As[r * 16 + (c4 ^ ((r >> 3) & 3))] = v;
    }
    __syncthreads();
    int jg = tid & 15;       // output col group (4 cols)
    int rg = tid >> 4;       // row group (8 rows)
    int r0 = rg * 8;
    int sw = rg & 3;         // swizzle key for this thread's rows
    float4 acc[8];
    #pragma unroll
    for (int rr = 0; rr < 8; ++rr) acc[rr] = make_float4(0.f, 0.f, 0.f, 0.f);
    #pragma unroll 2
    for (int kt = 0; kt < 16; ++kt) {
        float4 w0 = Ws[(kt * 4 + 0) * 16 + jg];
        float4 w1 = Ws[(kt * 4 + 1) * 16 + jg];
        float4 w2 = Ws[(kt * 4 + 2) * 16 + jg];
        float4 w3 = Ws[(kt * 4 + 3) * 16 + jg];
        int ac = kt ^ sw;
        #pragma unroll
        for (int rr = 0; rr < 8; ++rr) {
            float4 a = As[(r0 + rr) * 16 + ac];
            acc[rr].x = fmaf(a.x, w0.x, acc[rr].x);
            acc[rr].y = fmaf(a.x, w0.y, acc[rr].y);
            acc[rr].z = fmaf(a.x, w0.z, acc[rr].z);
            acc[rr].w = fmaf(a.x, w0.w, acc[rr].w);
            acc[rr].x = fmaf(a.y, w1.x, acc[rr].x);
            acc[rr].y = fmaf(a.y, w1.y, acc[rr].y);
            acc[rr].z = fmaf(a.y, w1.z, acc[rr].z);
            acc[rr].w = fmaf(a.y, w1.w, acc[rr].w);
            acc[rr].x = fmaf(a.z, w2.x, acc[rr].x);
            acc[rr].y = fmaf(a.z, w2.y, acc[rr].y);
            acc[rr].z = fmaf(a.z, w2.z, acc[rr].z);
            acc[rr].w = fmaf(a.z, w2.w, acc[rr].w);
            acc[rr].x = fmaf(a.w, w3.x, acc[rr].x);
            acc[rr].y = fmaf(a.w, w3.y, acc[rr].y);
            acc[rr].z = fmaf(a.w, w3.z, acc[rr].z);
            acc[rr].w = fmaf(a.w, w3.w, acc[rr].w);
        }
    }
    #pragma unroll
    for (int rr = 0; rr < 8; ++rr) {
        int r = rowbase + r0 + rr;
        if (r < n) *(float4*)&out[(size_t)r * 64 + jg * 4] = acc[rr];
    }
}

// ---- gather-aggregate, unrolled x4 for memory-level parallelism.
__global__ __launch_bounds__(TPB) void k_gather(const int* __restrict__ starts,
                                                const int2* __restrict__ edges,
                                                const float* __restrict__ hw,
                                                const float* __restrict__ dinv,
                                                const float* __restrict__ b,
                                                float* __restrict__ out,
                                                int n, int relu) {
    int idx = blockIdx.x * TPB + threadIdx.x;
    int node = idx >> 4;
    if (node >= n) return;
    int f = (idx & 15) << 2;
    int s0 = starts[node], s1 = starts[node + 1];
    float di = dinv[node];
    float sc = di * di;
    float4 hself = *(const float4*)&hw[(size_t)node * 64 + f];
    float4 bb = *(const float4*)&b[f];
    float4 acc;
    acc.x = fmaf(hself.x, sc, bb.x);
    acc.y = fmaf(hself.y, sc, bb.y);
    acc.z = fmaf(hself.z, sc, bb.z);
    acc.w = fmaf(hself.w, sc, bb.w);
    int e = s0;
    for (; e + 4 <= s1; e += 4) {
        int2 e0 = edges[e + 0];
        int2 e1 = edges[e + 1];
        int2 e2 = edges[e + 2];
        int2 e3 = edges[e + 3];
        float4 h0 = *(const float4*)&hw[(size_t)e0.x * 64 + f];
        float4 h1 = *(const float4*)&hw[(size_t)e1.x * 64 + f];
        float4 h2 = *(const float4*)&hw[(size_t)e2.x * 64 + f];
        float4 h3 = *(const float4*)&hw[(size_t)e3.x * 64 + f];
        float n0 = __int_as_float(e0.y), n1 = __int_as_float(e1.y);
        float n2 = __int_as_float(e2.y), n3 = __int_as_float(e3.y);
        acc.x = fmaf(h0.x, n0, acc.x); acc.y = fmaf(h0.y, n0, acc.y);
        acc.z = fmaf(h0.z, n0, acc.z); acc.w = fmaf(h0.w, n0, acc.w);
        acc.x = fmaf(h1.x, n1, acc.x); acc.y = fmaf(h1.y, n1, acc.y);
        acc.z = fmaf(h1.z, n1, acc.z); acc.w = fmaf(h1.w, n1, acc.w);
        acc.x = fmaf(h2.x, n2, acc.x); acc.y = fmaf(h2.y, n2, acc.y);
        acc.z = fmaf(h2.z, n2, acc.z); acc.w = fmaf(h2.w, n2, acc.w);
        acc.x = fmaf(h3.x, n3, acc.x); acc.y = fmaf(h3.y, n3, acc.y);
        acc.z = fmaf(h3.z, n3, acc.z); acc.w = fmaf(h3.w, n3, acc.w);
    }
    for (; e < s1; ++e) {
        int2 ed = edges[e];
        float nm = __int_as_float(ed.y);
        float4 h = *(const float4*)&hw[(size_t)ed.x * 64 + f];
        acc.x = fmaf(h.x, nm, acc.x);
        acc.y = fmaf(h.y, nm, acc.y);
        acc.z = fmaf(h.z, nm, acc.z);
        acc.w = fmaf(h.w, nm, acc.w);
    }
    if (relu) {
        acc.x = acc.x > 0.f ? acc.x : 0.f;
        acc.y = acc.y > 0.f ? acc.y : 0.f;
        acc.z = acc.z > 0.f ? acc.z : 0.f;
        acc.w = acc.w > 0.f ? acc.w : 0.f;
    }
    *(float4*)&out[(size_t)node * 64 + f] = acc;
}

extern "C" void kernel_launch(void* const* d_in, const int* in_sizes, int n_in,
                              void* d_out, int out_size, void* d_ws, size_t ws_size,
                              hipStream_t stream) {
    const float* x = (const float*)d_in[0];
    const int* ei = (const int*)d_in[1];      // int32 on device
    const float* ew = (const float*)d_in[2];
    const float* Wl[3] = {(const float*)d_in[3], (const float*)d_in[5], (const float*)d_in[7]};
    const float* Bl[3] = {(const float*)d_in[4], (const float*)d_in[6], (const float*)d_in[8]};

    const int n = in_sizes[0] / 64;
    const int E = in_sizes[2];
    const int* row = ei;       // edge_index[0]
    const int* col = ei + E;   // edge_index[1]
    float* out = (float*)d_out;

    const int nbk = (n + DNB - 1) >> DSH;                 // coarse buckets (<=1024 for n<=131072)
    const int p1b = (E + P1_CHUNK - 1) / P1_CHUNK;

    // workspace layout (256B aligned):
    // dinv[n] | hw[n*64] (bkt int2[E] aliased inside; hw written only after pass 2)
    // | starts[n+1] | chist[1024] | cbase[1025] | ccur[1024] | edges[E] int2
    char* ws = (char*)d_ws;
    size_t o = 0;
    float* dinv  = (float*)(ws + o);  o = (o + (size_t)n * 4 + 255) & ~(size_t)255;
    float* hw    = (float*)(ws + o);
    int2*  bkt   = (int2*)(ws + o);   o = (o + (size_t)n * 256 + 255) & ~(size_t)255;
    int* starts  = (int*)(ws + o);    o = (o + (size_t)(n + 1) * 4 + 255) & ~(size_t)255;
    int* chist   = (int*)(ws + o);    o = (o + 1024 * 4 + 255) & ~(size_t)255;
    int* cbase   = (int*)(ws + o);    o = (o + 1025 * 4 + 255) & ~(size_t)255;
    int* ccur    = (int*)(ws + o);    o = (o + 1024 * 4 + 255) & ~(size_t)255;
    int2* edges  = (int2*)(ws + o);

    // output 0 = x
    hipMemcpyAsync(out, x, (size_t)n * 64 * sizeof(float), hipMemcpyDeviceToDevice, stream);

    // CSR by destination: 2-level counting sort (+ fused deg/dinv in pass 2)
    hipMemsetAsync(chist, 0, (size_t)nbk * 4, stream);
    k_p0<<<p1b, TPB, 0, stream>>>(col, chist, E, nbk);
    k_scanb<<<1, 1024, 0, stream>>>(chist, cbase, ccur, nbk, E);
    k_p1<<<p1b, TPB, 0, stream>>>(row, col, ew, ccur, bkt, E, nbk);
    k_p2<<<nbk, TPB, 0, stream>>>(bkt, cbase, starts, edges, dinv, n, E);
    k_normcsr<<<(n + TPB - 1) / TPB, TPB, 0, stream>>>(starts, dinv, edges, n);

    const float* hin = x;
    for (int L = 0; L < 3; ++L) {
        float* oseg = out + (size_t)(L + 1) * n * 64;
        k_gemm64<<<(n + 127) / 128, TPB, 0, stream>>>(hin, Wl[L], hw, n);
        k_gather<<<(n * 16 + TPB - 1) / TPB, TPB, 0, stream>>>(starts, edges, hw, dinv, Bl[L], oseg, n, L < 2 ? 1 : 0);
        hin = oseg;
    }
}

// Round 3
// 434.037 us; speedup vs baseline: 1.6520x; 1.0108x over previous
//
#include <hip/hip_runtime.h>

// GCN: 3x (h@W -> gather-aggregate via CSR-by-dest + self-loop + bias [-> ReLU])
// Outputs: concat(x, h1, h2, h3), each [N,64] fp32.
// CSR via 2-level counting sort; deg/dinv fused into pass 2.
// R1: k_gemm64 128-row block, 8x4 register tile, b128 LDS, XOR-swizzled A staging.
// R2: fix R1 spill: unroll 2 + launch_bounds(TPB,3) (full unroll -> 256 VGPR -> spill).
// R3: (a) k_normcsr DELETED - norm factored as dinv[dst]*(sum dinv[src]*w*h) done in
//     gather (dinv is L2-resident, read is ~free vs the 256B hw row).
//     (b) k_gather: wave-per-node, 4 edges x 16 fchunks per wave, x2 unroll,
//     shfl_xor reduction - kills the quarter-wave divergence + serial walk.
//     (c) out0=x memcpy folded into gemm L0 staging (write-through).

#define TPB 256
#define P1_CHUNK 8192   // edges per block in pass0/pass1
#define DSH 7           // coarse bucket = dest >> DSH (128 dests/bucket)
#define DNB 128         // dests per bucket
#define STAGE_CAP 4096  // pass-2 LDS staging capacity (edges)

// ---- Pass 0: coarse histogram (per-block LDS hist, merged with few global atomics)
__global__ __launch_bounds__(TPB) void k_p0(const int* __restrict__ col,
                                            int* __restrict__ chist, int E, int nbk) {
    __shared__ int h[1024];
    int tid = threadIdx.x;
    for (int i = tid; i < nbk; i += TPB) h[i] = 0;
    __syncthreads();
    int s0 = blockIdx.x * P1_CHUNK;
    int s1 = min(s0 + P1_CHUNK, E);
    for (int i = s0 + tid; i < s1; i += TPB) atomicAdd(&h[col[i] >> DSH], 1);
    __syncthreads();
    for (int i = tid; i < nbk; i += TPB)
        if (h[i]) atomicAdd(&chist[i], h[i]);
}

// ---- Scan coarse buckets (single block), init cursor copy.
__global__ __launch_bounds__(1024) void k_scanb(const int* __restrict__ chist,
                                                int* __restrict__ cbase,
                                                int* __restrict__ ccur, int nbk, int E) {
    __shared__ int s[1024];
    int tid = threadIdx.x;
    int v = (tid < nbk) ? chist[tid] : 0;
    s[tid] = v;
    __syncthreads();
    for (int off = 1; off < 1024; off <<= 1) {
        int t = (tid >= off) ? s[tid - off] : 0;
        __syncthreads();
        s[tid] += t;
        __syncthreads();
    }
    if (tid < nbk) { int ex = s[tid] - v; cbase[tid] = ex; ccur[tid] = ex; }
    if (tid == 0) cbase[nbk] = E;
}

// ---- Pass 1: scatter edges into coarse-bucket runs (one global atomic per block-bucket).
// Packs (src | destlo<<20, w) so pass 2 doesn't need col[].
__global__ __launch_bounds__(TPB) void k_p1(const int* __restrict__ row,
                                            const int* __restrict__ col,
                                            const float* __restrict__ w,
                                            int* __restrict__ ccur,
                                            int2* __restrict__ bkt, int E, int nbk) {
    __shared__ int h[1024];
    __shared__ int base[1024];
    int tid = threadIdx.x;
    for (int i = tid; i < nbk; i += TPB) h[i] = 0;
    __syncthreads();
    int s0 = blockIdx.x * P1_CHUNK;
    int s1 = min(s0 + P1_CHUNK, E);
    for (int i = s0 + tid; i < s1; i += TPB) atomicAdd(&h[col[i] >> DSH], 1);
    __syncthreads();
    for (int i = tid; i < nbk; i += TPB) {
        int c = h[i];
        base[i] = c ? atomicAdd(&ccur[i], c) : 0;
        h[i] = 0;
    }
    __syncthreads();
    for (int i = s0 + tid; i < s1; i += TPB) {
        int c = col[i];
        int b = c >> DSH;
        int r = atomicAdd(&h[b], 1);
        bkt[base[b] + r] = make_int2(row[i] | ((c & (DNB - 1)) << 20), __float_as_int(w[i]));
    }
}

// ---- Pass 2: fine sort within bucket (LDS), write starts + edges coalesced,
//      and compute deg/dinv per dest (its edges are all here).
__global__ __launch_bounds__(TPB) void k_p2(const int2* __restrict__ bkt,
                                            const int* __restrict__ cbase,
                                            int* __restrict__ starts,
                                            int2* __restrict__ edges,
                                            float* __restrict__ dinv, int n, int E) {
    __shared__ int hist[DNB];
    __shared__ int curs[DNB];
    __shared__ int sc[DNB];
    __shared__ int2 stage[STAGE_CAP];
    int tid = threadIdx.x;
    int b = blockIdx.x;
    int s0 = cbase[b], s1 = cbase[b + 1];
    int cnt = s1 - s0;
    int nodeBase = b << DSH;
    if (tid < DNB) hist[tid] = 0;
    __syncthreads();
    for (int i = s0 + tid; i < s1; i += TPB)
        atomicAdd(&hist[(unsigned)bkt[i].x >> 20], 1);
    __syncthreads();
    int v = 0;
    if (tid < DNB) { v = hist[tid]; sc[tid] = v; }
    __syncthreads();
    for (int off = 1; off < DNB; off <<= 1) {
        int t = 0;
        if (tid < DNB && tid >= off) t = sc[tid - off];
        __syncthreads();
        if (tid < DNB) sc[tid] += t;
        __syncthreads();
    }
    if (tid < DNB) {
        int ex = sc[tid] - v;
        curs[tid] = ex;
        int node = nodeBase + tid;
        if (node < n) starts[node] = s0 + ex;
    }
    if (b == 0 && tid == 0) starts[n] = E;
    __syncthreads();
    if (cnt <= STAGE_CAP) {
        for (int i = s0 + tid; i < s1; i += TPB) {
            int2 ed = bkt[i];
            int d = (unsigned)ed.x >> 20;
            int r = atomicAdd(&curs[d], 1);
            stage[r] = make_int2(ed.x & 0xFFFFF, ed.y);
        }
        __syncthreads();
        for (int i = tid; i < cnt; i += TPB) edges[s0 + i] = stage[i];
        // deg/dinv from LDS stage: node tid's run = [sc[tid]-v, sc[tid])
        if (tid < DNB) {
            int node = nodeBase + tid;
            if (node < n) {
                float d = 1.0f;  // self-loop
                for (int j = sc[tid] - v; j < sc[tid]; ++j)
                    d += __int_as_float(stage[j].y);
                dinv[node] = rsqrtf(d);
            }
        }
    } else {  // overflow fallback: direct (uncoalesced but correct)
        for (int i = s0 + tid; i < s1; i += TPB) {
            int2 ed = bkt[i];
            int d = (unsigned)ed.x >> 20;
            int r = atomicAdd(&curs[d], 1);
            edges[s0 + r] = make_int2(ed.x & 0xFFFFF, ed.y);
        }
        __syncthreads();
        if (tid < DNB) {
            int node = nodeBase + tid;
            if (node < n) {
                float d = 1.0f;
                for (int j = sc[tid] - v; j < sc[tid]; ++j)
                    d += __int_as_float(edges[s0 + j].y);
                dinv[node] = rsqrtf(d);
            }
        }
    }
}

// ---- out[N,64] = in[N,64] @ W[64,64].
// 128 rows/block, 256 threads; thread tile = 8 rows x 4 cols.
// b128 LDS, XOR-swizzled A staging; unroll 2 (full unroll spills);
// launch_bounds(TPB,3) matches the 48KB-LDS occupancy cap.
// cp != nullptr: write staged input rows through to cp (fuses the out0=x memcpy).
__global__ __launch_bounds__(TPB, 3) void k_gemm64(const float* __restrict__ in,
                                                   const float* __restrict__ Wg,
                                                   float* __restrict__ out,
                                                   float* __restrict__ cp, int n) {
    __shared__ float4 Ws[1024];   // [64 k][16 j4]
    __shared__ float4 As[2048];   // [128 r][16 c4], swizzled
    int tid = threadIdx.x;
    const float4* Wf4 = (const float4*)Wg;
    #pragma unroll
    for (int i = 0; i < 4; ++i) Ws[i * 256 + tid] = Wf4[i * 256 + tid];
    int rowbase = blockIdx.x * 128;
    const float4* Af4 = (const float4*)in;
    #pragma unroll
    for (int i = 0; i < 8; ++i) {
        int f4 = i * 256 + tid;
        int r = f4 >> 4, c4 = f4 & 15;
        float4 v = make_float4(0.f, 0.f, 0.f, 0.f);
        if (rowbase + r < n) {
            v = Af4[(size_t)(rowbase + r) * 16 + c4];
            if (cp) *(float4*)&cp[((size_t)(rowbase + r) * 16 + c4) * 4] = v;
        }
        As[r * 16 + (c4 ^ ((r >> 3) & 3))] = v;
    }
    __syncthreads();
    int jg = tid & 15;       // output col group (4 cols)
    int rg = tid >> 4;       // row group (8 rows)
    int r0 = rg * 8;
    int sw = rg & 3;         // swizzle key for this thread's rows
    float4 acc[8];
    #pragma unroll
    for (int rr = 0; rr < 8; ++rr) acc[rr] = make_float4(0.f, 0.f, 0.f, 0.f);
    #pragma unroll 2
    for (int kt = 0; kt < 16; ++kt) {
        float4 w0 = Ws[(kt * 4 + 0) * 16 + jg];
        float4 w1 = Ws[(kt * 4 + 1) * 16 + jg];
        float4 w2 = Ws[(kt * 4 + 2) * 16 + jg];
        float4 w3 = Ws[(kt * 4 + 3) * 16 + jg];
        int ac = kt ^ sw;
        #pragma unroll
        for (int rr = 0; rr < 8; ++rr) {
            float4 a = As[(r0 + rr) * 16 + ac];
            acc[rr].x = fmaf(a.x, w0.x, acc[rr].x);
            acc[rr].y = fmaf(a.x, w0.y, acc[rr].y);
            acc[rr].z = fmaf(a.x, w0.z, acc[rr].z);
            acc[rr].w = fmaf(a.x, w0.w, acc[rr].w);
            acc[rr].x = fmaf(a.y, w1.x, acc[rr].x);
            acc[rr].y = fmaf(a.y, w1.y, acc[rr].y);
            acc[rr].z = fmaf(a.y, w1.z, acc[rr].z);
            acc[rr].w = fmaf(a.y, w1.w, acc[rr].w);
            acc[rr].x = fmaf(a.z, w2.x, acc[rr].x);
            acc[rr].y = fmaf(a.z, w2.y, acc[rr].y);
            acc[rr].z = fmaf(a.z, w2.z, acc[rr].z);
            acc[rr].w = fmaf(a.z, w2.w, acc[rr].w);
            acc[rr].x = fmaf(a.w, w3.x, acc[rr].x);
            acc[rr].y = fmaf(a.w, w3.y, acc[rr].y);
            acc[rr].z = fmaf(a.w, w3.z, acc[rr].z);
            acc[rr].w = fmaf(a.w, w3.w, acc[rr].w);
        }
    }
    #pragma unroll
    for (int rr = 0; rr < 8; ++rr) {
        int r = rowbase + r0 + rr;
        if (r < n) *(float4*)&out[(size_t)r * 64 + jg * 4] = acc[rr];
    }
}

// ---- gather-aggregate: one wave per node.
// lane = eslot(0..3) x fchunk(0..15): 4 edges in flight x 16 float4-chunks,
// each edge's hw row read as a coalesced 256B segment. x2 unroll -> 8 edges in
// flight per wave. norm computed on the fly: acc_inner = sum dinv[src]*w*h[src];
// out = dinv[dst]*(acc_inner + dinv[dst]*h[self]) + b. shfl_xor butterfly over eslots.
__global__ __launch_bounds__(TPB) void k_gather(const int* __restrict__ starts,
                                                const int2* __restrict__ edges,
                                                const float* __restrict__ hw,
                                                const float* __restrict__ dinv,
                                                const float* __restrict__ b,
                                                float* __restrict__ out,
                                                int n, int relu) {
    int node = blockIdx.x * 4 + (threadIdx.x >> 6);
    if (node >= n) return;
    int lane = threadIdx.x & 63;
    int eslot = lane >> 4;
    int f = (lane & 15) << 2;
    int s0 = starts[node], s1 = starts[node + 1];
    float4 acc = make_float4(0.f, 0.f, 0.f, 0.f);
    int e = s0 + eslot;
    for (; e + 4 < s1; e += 8) {
        int2 ed0 = edges[e];
        int2 ed1 = edges[e + 4];
        float nm0 = dinv[ed0.x] * __int_as_float(ed0.y);
        float nm1 = dinv[ed1.x] * __int_as_float(ed1.y);
        float4 h0 = *(const float4*)&hw[(size_t)ed0.x * 64 + f];
        float4 h1 = *(const float4*)&hw[(size_t)ed1.x * 64 + f];
        acc.x = fmaf(h0.x, nm0, acc.x);
        acc.y = fmaf(h0.y, nm0, acc.y);
        acc.z = fmaf(h0.z, nm0, acc.z);
        acc.w = fmaf(h0.w, nm0, acc.w);
        acc.x = fmaf(h1.x, nm1, acc.x);
        acc.y = fmaf(h1.y, nm1, acc.y);
        acc.z = fmaf(h1.z, nm1, acc.z);
        acc.w = fmaf(h1.w, nm1, acc.w);
    }
    if (e < s1) {
        int2 ed = edges[e];
        float nm = dinv[ed.x] * __int_as_float(ed.y);
        float4 h = *(const float4*)&hw[(size_t)ed.x * 64 + f];
        acc.x = fmaf(h.x, nm, acc.x);
        acc.y = fmaf(h.y, nm, acc.y);
        acc.z = fmaf(h.z, nm, acc.z);
        acc.w = fmaf(h.w, nm, acc.w);
    }
    // reduce the 4 edge-slots (all lanes end with the full sum)
    acc.x += __shfl_xor(acc.x, 16);
    acc.y += __shfl_xor(acc.y, 16);
    acc.z += __shfl_xor(acc.z, 16);
    acc.w += __shfl_xor(acc.w, 16);
    acc.x += __shfl_xor(acc.x, 32);
    acc.y += __shfl_xor(acc.y, 32);
    acc.z += __shfl_xor(acc.z, 32);
    acc.w += __shfl_xor(acc.w, 32);
    if (eslot == 0) {
        float di = dinv[node];
        float4 hs = *(const float4*)&hw[(size_t)node * 64 + f];
        float4 bb = *(const float4*)&b[f];
        float ix = fmaf(hs.x, di, acc.x);
        float iy = fmaf(hs.y, di, acc.y);
        float iz = fmaf(hs.z, di, acc.z);
        float iw = fmaf(hs.w, di, acc.w);
        float4 o;
        o.x = fmaf(ix, di, bb.x);
        o.y = fmaf(iy, di, bb.y);
        o.z = fmaf(iz, di, bb.z);
        o.w = fmaf(iw, di, bb.w);
        if (relu) {
            o.x = o.x > 0.f ? o.x : 0.f;
            o.y = o.y > 0.f ? o.y : 0.f;
            o.z = o.z > 0.f ? o.z : 0.f;
            o.w = o.w > 0.f ? o.w : 0.f;
        }
        *(float4*)&out[(size_t)node * 64 + f] = o;
    }
}

extern "C" void kernel_launch(void* const* d_in, const int* in_sizes, int n_in,
                              void* d_out, int out_size, void* d_ws, size_t ws_size,
                              hipStream_t stream) {
    const float* x = (const float*)d_in[0];
    const int* ei = (const int*)d_in[1];      // int32 on device
    const float* ew = (const float*)d_in[2];
    const float* Wl[3] = {(const float*)d_in[3], (const float*)d_in[5], (const float*)d_in[7]};
    const float* Bl[3] = {(const float*)d_in[4], (const float*)d_in[6], (const float*)d_in[8]};

    const int n = in_sizes[0] / 64;
    const int E = in_sizes[2];
    const int* row = ei;       // edge_index[0]
    const int* col = ei + E;   // edge_index[1]
    float* out = (float*)d_out;

    const int nbk = (n + DNB - 1) >> DSH;                 // coarse buckets (<=1024 for n<=131072)
    const int p1b = (E + P1_CHUNK - 1) / P1_CHUNK;

    // workspace layout (256B aligned):
    // dinv[n] | hw[n*64] (bkt int2[E] aliased inside; hw written only after pass 2)
    // | starts[n+1] | chist[1024] | cbase[1025] | ccur[1024] | edges[E] int2
    char* ws = (char*)d_ws;
    size_t o = 0;
    float* dinv  = (float*)(ws + o);  o = (o + (size_t)n * 4 + 255) & ~(size_t)255;
    float* hw    = (float*)(ws + o);
    int2*  bkt   = (int2*)(ws + o);   o = (o + (size_t)n * 256 + 255) & ~(size_t)255;
    int* starts  = (int*)(ws + o);    o = (o + (size_t)(n + 1) * 4 + 255) & ~(size_t)255;
    int* chist   = (int*)(ws + o);    o = (o + 1024 * 4 + 255) & ~(size_t)255;
    int* cbase   = (int*)(ws + o);    o = (o + 1025 * 4 + 255) & ~(size_t)255;
    int* ccur    = (int*)(ws + o);    o = (o + 1024 * 4 + 255) & ~(size_t)255;
    int2* edges  = (int2*)(ws + o);

    // CSR by destination: 2-level counting sort (+ fused deg/dinv in pass 2)
    hipMemsetAsync(chist, 0, (size_t)nbk * 4, stream);
    k_p0<<<p1b, TPB, 0, stream>>>(col, chist, E, nbk);
    k_scanb<<<1, 1024, 0, stream>>>(chist, cbase, ccur, nbk, E);
    k_p1<<<p1b, TPB, 0, stream>>>(row, col, ew, ccur, bkt, E, nbk);
    k_p2<<<nbk, TPB, 0, stream>>>(bkt, cbase, starts, edges, dinv, n, E);
    // norm folded into k_gather (edges[].y stays raw w)

    const float* hin = x;
    for (int L = 0; L < 3; ++L) {
        float* oseg = out + (size_t)(L + 1) * n * 64;
        // L==0: write-through x -> out segment 0 (replaces memcpy)
        k_gemm64<<<(n + 127) / 128, TPB, 0, stream>>>(hin, Wl[L], hw, L == 0 ? out : nullptr, n);
        k_gather<<<(n + 3) / 4, TPB, 0, stream>>>(starts, edges, hw, dinv, Bl[L], oseg, n, L < 2 ? 1 : 0);
        hin = oseg;
    }
}

// Round 4
// 424.354 us; speedup vs baseline: 1.6897x; 1.0228x over previous
//
#include <hip/hip_runtime.h>
#include <hip/hip_fp16.h>

// GCN: 3x (h@W -> gather-aggregate via CSR-by-dest + self-loop + bias [-> ReLU])
// Outputs: concat(x, h1, h2, h3), each [N,64] fp32.
// CSR via 2-level counting sort; deg/dinv fused into pass 2.
// R1: k_gemm64 128-row block, 8x4 register tile, b128 LDS, XOR-swizzled A staging.
// R2: fix R1 spill: unroll 2 + launch_bounds(TPB,3).
// R3: normcsr deleted (norm factored into gather); wave-per-node gather; memcpy fused.
// R4: gather is fabric-bound (327MB random row reads @ ~3.4TB/s = ~97us/layer).
//     (a) hw stored as fp16, dinv[src] pre-baked in gemm epilogue -> 164MB/layer,
//         edge->row dep chain shortened (no per-edge dinv load).
//     (b) nontemporal edge loads (preserve L2 for hw rows).
//     (c) P1_CHUNK 8192->4096 (p0/p1 CU coverage 157->313 blocks).

#define TPB 256
#define P1_CHUNK 4096   // edges per block in pass0/pass1
#define DSH 7           // coarse bucket = dest >> DSH (128 dests/bucket)
#define DNB 128         // dests per bucket
#define STAGE_CAP 4096  // pass-2 LDS staging capacity (edges)

// ---- Pass 0: coarse histogram (per-block LDS hist, merged with few global atomics)
__global__ __launch_bounds__(TPB) void k_p0(const int* __restrict__ col,
                                            int* __restrict__ chist, int E, int nbk) {
    __shared__ int h[1024];
    int tid = threadIdx.x;
    for (int i = tid; i < nbk; i += TPB) h[i] = 0;
    __syncthreads();
    int s0 = blockIdx.x * P1_CHUNK;
    int s1 = min(s0 + P1_CHUNK, E);
    for (int i = s0 + tid; i < s1; i += TPB) atomicAdd(&h[col[i] >> DSH], 1);
    __syncthreads();
    for (int i = tid; i < nbk; i += TPB)
        if (h[i]) atomicAdd(&chist[i], h[i]);
}

// ---- Scan coarse buckets (single block), init cursor copy.
__global__ __launch_bounds__(1024) void k_scanb(const int* __restrict__ chist,
                                                int* __restrict__ cbase,
                                                int* __restrict__ ccur, int nbk, int E) {
    __shared__ int s[1024];
    int tid = threadIdx.x;
    int v = (tid < nbk) ? chist[tid] : 0;
    s[tid] = v;
    __syncthreads();
    for (int off = 1; off < 1024; off <<= 1) {
        int t = (tid >= off) ? s[tid - off] : 0;
        __syncthreads();
        s[tid] += t;
        __syncthreads();
    }
    if (tid < nbk) { int ex = s[tid] - v; cbase[tid] = ex; ccur[tid] = ex; }
    if (tid == 0) cbase[nbk] = E;
}

// ---- Pass 1: scatter edges into coarse-bucket runs (one global atomic per block-bucket).
// Packs (src | destlo<<20, w) so pass 2 doesn't need col[].
__global__ __launch_bounds__(TPB) void k_p1(const int* __restrict__ row,
                                            const int* __restrict__ col,
                                            const float* __restrict__ w,
                                            int* __restrict__ ccur,
                                            int2* __restrict__ bkt, int E, int nbk) {
    __shared__ int h[1024];
    __shared__ int base[1024];
    int tid = threadIdx.x;
    for (int i = tid; i < nbk; i += TPB) h[i] = 0;
    __syncthreads();
    int s0 = blockIdx.x * P1_CHUNK;
    int s1 = min(s0 + P1_CHUNK, E);
    for (int i = s0 + tid; i < s1; i += TPB) atomicAdd(&h[col[i] >> DSH], 1);
    __syncthreads();
    for (int i = tid; i < nbk; i += TPB) {
        int c = h[i];
        base[i] = c ? atomicAdd(&ccur[i], c) : 0;
        h[i] = 0;
    }
    __syncthreads();
    for (int i = s0 + tid; i < s1; i += TPB) {
        int c = col[i];
        int b = c >> DSH;
        int r = atomicAdd(&h[b], 1);
        bkt[base[b] + r] = make_int2(row[i] | ((c & (DNB - 1)) << 20), __float_as_int(w[i]));
    }
}

// ---- Pass 2: fine sort within bucket (LDS), write starts + edges coalesced,
//      and compute deg/dinv per dest (its edges are all here).
__global__ __launch_bounds__(TPB) void k_p2(const int2* __restrict__ bkt,
                                            const int* __restrict__ cbase,
                                            int* __restrict__ starts,
                                            int2* __restrict__ edges,
                                            float* __restrict__ dinv, int n, int E) {
    __shared__ int hist[DNB];
    __shared__ int curs[DNB];
    __shared__ int sc[DNB];
    __shared__ int2 stage[STAGE_CAP];
    int tid = threadIdx.x;
    int b = blockIdx.x;
    int s0 = cbase[b], s1 = cbase[b + 1];
    int cnt = s1 - s0;
    int nodeBase = b << DSH;
    if (tid < DNB) hist[tid] = 0;
    __syncthreads();
    for (int i = s0 + tid; i < s1; i += TPB)
        atomicAdd(&hist[(unsigned)bkt[i].x >> 20], 1);
    __syncthreads();
    int v = 0;
    if (tid < DNB) { v = hist[tid]; sc[tid] = v; }
    __syncthreads();
    for (int off = 1; off < DNB; off <<= 1) {
        int t = 0;
        if (tid < DNB && tid >= off) t = sc[tid - off];
        __syncthreads();
        if (tid < DNB) sc[tid] += t;
        __syncthreads();
    }
    if (tid < DNB) {
        int ex = sc[tid] - v;
        curs[tid] = ex;
        int node = nodeBase + tid;
        if (node < n) starts[node] = s0 + ex;
    }
    if (b == 0 && tid == 0) starts[n] = E;
    __syncthreads();
    if (cnt <= STAGE_CAP) {
        for (int i = s0 + tid; i < s1; i += TPB) {
            int2 ed = bkt[i];
            int d = (unsigned)ed.x >> 20;
            int r = atomicAdd(&curs[d], 1);
            stage[r] = make_int2(ed.x & 0xFFFFF, ed.y);
        }
        __syncthreads();
        for (int i = tid; i < cnt; i += TPB) edges[s0 + i] = stage[i];
        // deg/dinv from LDS stage: node tid's run = [sc[tid]-v, sc[tid])
        if (tid < DNB) {
            int node = nodeBase + tid;
            if (node < n) {
                float d = 1.0f;  // self-loop
                for (int j = sc[tid] - v; j < sc[tid]; ++j)
                    d += __int_as_float(stage[j].y);
                dinv[node] = rsqrtf(d);
            }
        }
    } else {  // overflow fallback: direct (uncoalesced but correct)
        for (int i = s0 + tid; i < s1; i += TPB) {
            int2 ed = bkt[i];
            int d = (unsigned)ed.x >> 20;
            int r = atomicAdd(&curs[d], 1);
            edges[s0 + r] = make_int2(ed.x & 0xFFFFF, ed.y);
        }
        __syncthreads();
        if (tid < DNB) {
            int node = nodeBase + tid;
            if (node < n) {
                float d = 1.0f;
                for (int j = sc[tid] - v; j < sc[tid]; ++j)
                    d += __int_as_float(edges[s0 + j].y);
                dinv[node] = rsqrtf(d);
            }
        }
    }
}

// ---- hw'[N,64] (fp16) = dinv[r] * (in[N,64] @ W[64,64]).
// 128 rows/block, 256 threads; thread tile = 8 rows x 4 cols.
// b128 LDS, XOR-swizzled A staging; unroll 2 (full unroll spills);
// launch_bounds(TPB,3) matches the 48KB-LDS occupancy cap.
// Epilogue: scale by dinv[r], convert to fp16 (halves gather fabric traffic;
// bakes the per-edge dinv[src] factor into the row).
// cp != nullptr: write staged fp32 input rows through to cp (fuses out0=x memcpy).
__global__ __launch_bounds__(TPB, 3) void k_gemm64(const float* __restrict__ in,
                                                   const float* __restrict__ Wg,
                                                   __half* __restrict__ hwh,
                                                   const float* __restrict__ dinvg,
                                                   float* __restrict__ cp, int n) {
    __shared__ float4 Ws[1024];   // [64 k][16 j4]
    __shared__ float4 As[2048];   // [128 r][16 c4], swizzled
    int tid = threadIdx.x;
    const float4* Wf4 = (const float4*)Wg;
    #pragma unroll
    for (int i = 0; i < 4; ++i) Ws[i * 256 + tid] = Wf4[i * 256 + tid];
    int rowbase = blockIdx.x * 128;
    const float4* Af4 = (const float4*)in;
    #pragma unroll
    for (int i = 0; i < 8; ++i) {
        int f4 = i * 256 + tid;
        int r = f4 >> 4, c4 = f4 & 15;
        float4 v = make_float4(0.f, 0.f, 0.f, 0.f);
        if (rowbase + r < n) {
            v = Af4[(size_t)(rowbase + r) * 16 + c4];
            if (cp) *(float4*)&cp[((size_t)(rowbase + r) * 16 + c4) * 4] = v;
        }
        As[r * 16 + (c4 ^ ((r >> 3) & 3))] = v;
    }
    __syncthreads();
    int jg = tid & 15;       // output col group (4 cols)
    int rg = tid >> 4;       // row group (8 rows)
    int r0 = rg * 8;
    int sw = rg & 3;         // swizzle key for this thread's rows
    float4 acc[8];
    #pragma unroll
    for (int rr = 0; rr < 8; ++rr) acc[rr] = make_float4(0.f, 0.f, 0.f, 0.f);
    #pragma unroll 2
    for (int kt = 0; kt < 16; ++kt) {
        float4 w0 = Ws[(kt * 4 + 0) * 16 + jg];
        float4 w1 = Ws[(kt * 4 + 1) * 16 + jg];
        float4 w2 = Ws[(kt * 4 + 2) * 16 + jg];
        float4 w3 = Ws[(kt * 4 + 3) * 16 + jg];
        int ac = kt ^ sw;
        #pragma unroll
        for (int rr = 0; rr < 8; ++rr) {
            float4 a = As[(r0 + rr) * 16 + ac];
            acc[rr].x = fmaf(a.x, w0.x, acc[rr].x);
            acc[rr].y = fmaf(a.x, w0.y, acc[rr].y);
            acc[rr].z = fmaf(a.x, w0.z, acc[rr].z);
            acc[rr].w = fmaf(a.x, w0.w, acc[rr].w);
            acc[rr].x = fmaf(a.y, w1.x, acc[rr].x);
            acc[rr].y = fmaf(a.y, w1.y, acc[rr].y);
            acc[rr].z = fmaf(a.y, w1.z, acc[rr].z);
            acc[rr].w = fmaf(a.y, w1.w, acc[rr].w);
            acc[rr].x = fmaf(a.z, w2.x, acc[rr].x);
            acc[rr].y = fmaf(a.z, w2.y, acc[rr].y);
            acc[rr].z = fmaf(a.z, w2.z, acc[rr].z);
            acc[rr].w = fmaf(a.z, w2.w, acc[rr].w);
            acc[rr].x = fmaf(a.w, w3.x, acc[rr].x);
            acc[rr].y = fmaf(a.w, w3.y, acc[rr].y);
            acc[rr].z = fmaf(a.w, w3.z, acc[rr].z);
            acc[rr].w = fmaf(a.w, w3.w, acc[rr].w);
        }
    }
    #pragma unroll
    for (int rr = 0; rr < 8; ++rr) {
        int r = rowbase + r0 + rr;
        if (r < n) {
            float di = dinvg[r];
            ushort4 s;
            s.x = __half_as_ushort(__float2half(acc[rr].x * di));
            s.y = __half_as_ushort(__float2half(acc[rr].y * di));
            s.z = __half_as_ushort(__float2half(acc[rr].z * di));
            s.w = __half_as_ushort(__float2half(acc[rr].w * di));
            *(ushort4*)&hwh[(size_t)r * 64 + jg * 4] = s;
        }
    }
}

// ---- gather-aggregate: one wave per node, fp16 rows (dinv pre-baked).
// lane = eslot(0..3) x fchunk(0..15): 4 edges in flight x 16 half4-chunks,
// each edge's hw' row read as a coalesced 128B segment; x2 unroll -> 8 rows in
// flight per wave. out = dinv[dst]*(hw'[self] + sum w*hw'[src]) + b.
// Edge loads nontemporal (streamed once; keep L2 for hw' rows).
__global__ __launch_bounds__(TPB) void k_gather(const int* __restrict__ starts,
                                                const int2* __restrict__ edges,
                                                const __half* __restrict__ hwh,
                                                const float* __restrict__ dinv,
                                                const float* __restrict__ b,
                                                float* __restrict__ out,
                                                int n, int relu) {
    int node = blockIdx.x * 4 + (threadIdx.x >> 6);
    if (node >= n) return;
    int lane = threadIdx.x & 63;
    int eslot = lane >> 4;
    int f = (lane & 15) << 2;   // half-index within 64-half row
    int s0 = starts[node], s1 = starts[node + 1];
    float4 acc = make_float4(0.f, 0.f, 0.f, 0.f);
    const long long* epk = (const long long*)edges;
    int e = s0 + eslot;
    for (; e + 4 < s1; e += 8) {
        long long ev0 = __builtin_nontemporal_load(&epk[e]);
        long long ev1 = __builtin_nontemporal_load(&epk[e + 4]);
        ushort4 u0 = *(const ushort4*)&hwh[(size_t)(int)ev0 * 64 + f];
        ushort4 u1 = *(const ushort4*)&hwh[(size_t)(int)ev1 * 64 + f];
        float w0 = __int_as_float((int)(ev0 >> 32));
        float w1 = __int_as_float((int)(ev1 >> 32));
        acc.x = fmaf(__half2float(__ushort_as_half(u0.x)), w0, acc.x);
        acc.y = fmaf(__half2float(__ushort_as_half(u0.y)), w0, acc.y);
        acc.z = fmaf(__half2float(__ushort_as_half(u0.z)), w0, acc.z);
        acc.w = fmaf(__half2float(__ushort_as_half(u0.w)), w0, acc.w);
        acc.x = fmaf(__half2float(__ushort_as_half(u1.x)), w1, acc.x);
        acc.y = fmaf(__half2float(__ushort_as_half(u1.y)), w1, acc.y);
        acc.z = fmaf(__half2float(__ushort_as_half(u1.z)), w1, acc.z);
        acc.w = fmaf(__half2float(__ushort_as_half(u1.w)), w1, acc.w);
    }
    if (e < s1) {
        long long ev = __builtin_nontemporal_load(&epk[e]);
        ushort4 u = *(const ushort4*)&hwh[(size_t)(int)ev * 64 + f];
        float w = __int_as_float((int)(ev >> 32));
        acc.x = fmaf(__half2float(__ushort_as_half(u.x)), w, acc.x);
        acc.y = fmaf(__half2float(__ushort_as_half(u.y)), w, acc.y);
        acc.z = fmaf(__half2float(__ushort_as_half(u.z)), w, acc.z);
        acc.w = fmaf(__half2float(__ushort_as_half(u.w)), w, acc.w);
    }
    // reduce the 4 edge-slots
    acc.x += __shfl_xor(acc.x, 16);
    acc.y += __shfl_xor(acc.y, 16);
    acc.z += __shfl_xor(acc.z, 16);
    acc.w += __shfl_xor(acc.w, 16);
    acc.x += __shfl_xor(acc.x, 32);
    acc.y += __shfl_xor(acc.y, 32);
    acc.z += __shfl_xor(acc.z, 32);
    acc.w += __shfl_xor(acc.w, 32);
    if (eslot == 0) {
        float di = dinv[node];
        ushort4 us = *(const ushort4*)&hwh[(size_t)node * 64 + f];
        float4 bb = *(const float4*)&b[f];
        float4 o;
        o.x = fmaf(__half2float(__ushort_as_half(us.x)) + acc.x, di, bb.x);
        o.y = fmaf(__half2float(__ushort_as_half(us.y)) + acc.y, di, bb.y);
        o.z = fmaf(__half2float(__ushort_as_half(us.z)) + acc.z, di, bb.z);
        o.w = fmaf(__half2float(__ushort_as_half(us.w)) + acc.w, di, bb.w);
        if (relu) {
            o.x = o.x > 0.f ? o.x : 0.f;
            o.y = o.y > 0.f ? o.y : 0.f;
            o.z = o.z > 0.f ? o.z : 0.f;
            o.w = o.w > 0.f ? o.w : 0.f;
        }
        *(float4*)&out[(size_t)node * 64 + f] = o;
    }
}

extern "C" void kernel_launch(void* const* d_in, const int* in_sizes, int n_in,
                              void* d_out, int out_size, void* d_ws, size_t ws_size,
                              hipStream_t stream) {
    const float* x = (const float*)d_in[0];
    const int* ei = (const int*)d_in[1];      // int32 on device
    const float* ew = (const float*)d_in[2];
    const float* Wl[3] = {(const float*)d_in[3], (const float*)d_in[5], (const float*)d_in[7]};
    const float* Bl[3] = {(const float*)d_in[4], (const float*)d_in[6], (const float*)d_in[8]};

    const int n = in_sizes[0] / 64;
    const int E = in_sizes[2];
    const int* row = ei;       // edge_index[0]
    const int* col = ei + E;   // edge_index[1]
    float* out = (float*)d_out;

    const int nbk = (n + DNB - 1) >> DSH;                 // coarse buckets (<=1024 for n<=131072)
    const int p1b = (E + P1_CHUNK - 1) / P1_CHUNK;

    // workspace layout (256B aligned):
    // dinv[n] | hwh fp16[n*64] (bkt int2[E] aliased; hwh written only after pass 2)
    // | starts[n+1] | chist[1024] | cbase[1025] | ccur[1024] | edges[E] int2
    char* ws = (char*)d_ws;
    size_t o = 0;
    float* dinv  = (float*)(ws + o);  o = (o + (size_t)n * 4 + 255) & ~(size_t)255;
    __half* hwh  = (__half*)(ws + o);
    int2*  bkt   = (int2*)(ws + o);
    {
        size_t hb = (size_t)n * 128, bb = (size_t)E * 8;
        o = (o + (hb > bb ? hb : bb) + 255) & ~(size_t)255;
    }
    int* starts  = (int*)(ws + o);    o = (o + (size_t)(n + 1) * 4 + 255) & ~(size_t)255;
    int* chist   = (int*)(ws + o);    o = (o + 1024 * 4 + 255) & ~(size_t)255;
    int* cbase   = (int*)(ws + o);    o = (o + 1025 * 4 + 255) & ~(size_t)255;
    int* ccur    = (int*)(ws + o);    o = (o + 1024 * 4 + 255) & ~(size_t)255;
    int2* edges  = (int2*)(ws + o);

    // CSR by destination: 2-level counting sort (+ fused deg/dinv in pass 2)
    hipMemsetAsync(chist, 0, (size_t)nbk * 4, stream);
    k_p0<<<p1b, TPB, 0, stream>>>(col, chist, E, nbk);
    k_scanb<<<1, 1024, 0, stream>>>(chist, cbase, ccur, nbk, E);
    k_p1<<<p1b, TPB, 0, stream>>>(row, col, ew, ccur, bkt, E, nbk);
    k_p2<<<nbk, TPB, 0, stream>>>(bkt, cbase, starts, edges, dinv, n, E);
    // norm folded into gather; dinv[src] baked into hwh by gemm epilogue

    const float* hin = x;
    for (int L = 0; L < 3; ++L) {
        float* oseg = out + (size_t)(L + 1) * n * 64;
        // L==0: write-through x -> out segment 0 (replaces memcpy)
        k_gemm64<<<(n + 127) / 128, TPB, 0, stream>>>(hin, Wl[L], hwh, dinv, L == 0 ? out : nullptr, n);
        k_gather<<<(n + 3) / 4, TPB, 0, stream>>>(starts, edges, hwh, dinv, Bl[L], oseg, n, L < 2 ? 1 : 0);
        hin = oseg;
    }
}

// Round 5
// 368.835 us; speedup vs baseline: 1.9440x; 1.1505x over previous
//
#include <hip/hip_runtime.h>
#include <hip/hip_fp16.h>

// GCN: 3x (h@W -> gather-aggregate via CSR-by-dest + self-loop + bias [-> ReLU])
// Outputs: concat(x, h1, h2, h3), each [N,64] fp32.
// CSR via 2-level counting sort; deg/dinv fused into pass 2.
// R1: k_gemm64 128-row block, 8x4 register tile, b128 LDS, XOR-swizzled A staging.
// R2: fix R1 spill: unroll 2 + launch_bounds(TPB,3).
// R3: normcsr deleted (norm factored into gather); memcpy fused into gemm L0.
// R4: hw stored fp16 with dinv[src] baked (halved gather bytes; only -10us => gather
//     is LATENCY-bound, not byte/transaction-bound).
// R5: gather MLP-depth rewrite: wave-per-node, eslot=1 (64 lanes = one 128B row,
//     lane=feature), wave-uniform scalar edge loads, 8/4/2/1 unroll ladder ->
//     ~5-6 row loads in flight per wave (was ~1-2). No shfl reduction needed.

#define TPB 256
#define P1_CHUNK 4096   // edges per block in pass0/pass1
#define DSH 7           // coarse bucket = dest >> DSH (128 dests/bucket)
#define DNB 128         // dests per bucket
#define STAGE_CAP 4096  // pass-2 LDS staging capacity (edges)

// ---- Pass 0: coarse histogram (per-block LDS hist, merged with few global atomics)
__global__ __launch_bounds__(TPB) void k_p0(const int* __restrict__ col,
                                            int* __restrict__ chist, int E, int nbk) {
    __shared__ int h[1024];
    int tid = threadIdx.x;
    for (int i = tid; i < nbk; i += TPB) h[i] = 0;
    __syncthreads();
    int s0 = blockIdx.x * P1_CHUNK;
    int s1 = min(s0 + P1_CHUNK, E);
    for (int i = s0 + tid; i < s1; i += TPB) atomicAdd(&h[col[i] >> DSH], 1);
    __syncthreads();
    for (int i = tid; i < nbk; i += TPB)
        if (h[i]) atomicAdd(&chist[i], h[i]);
}

// ---- Scan coarse buckets (single block), init cursor copy.
__global__ __launch_bounds__(1024) void k_scanb(const int* __restrict__ chist,
                                                int* __restrict__ cbase,
                                                int* __restrict__ ccur, int nbk, int E) {
    __shared__ int s[1024];
    int tid = threadIdx.x;
    int v = (tid < nbk) ? chist[tid] : 0;
    s[tid] = v;
    __syncthreads();
    for (int off = 1; off < 1024; off <<= 1) {
        int t = (tid >= off) ? s[tid - off] : 0;
        __syncthreads();
        s[tid] += t;
        __syncthreads();
    }
    if (tid < nbk) { int ex = s[tid] - v; cbase[tid] = ex; ccur[tid] = ex; }
    if (tid == 0) cbase[nbk] = E;
}

// ---- Pass 1: scatter edges into coarse-bucket runs (one global atomic per block-bucket).
// Packs (src | destlo<<20, w) so pass 2 doesn't need col[].
__global__ __launch_bounds__(TPB) void k_p1(const int* __restrict__ row,
                                            const int* __restrict__ col,
                                            const float* __restrict__ w,
                                            int* __restrict__ ccur,
                                            int2* __restrict__ bkt, int E, int nbk) {
    __shared__ int h[1024];
    __shared__ int base[1024];
    int tid = threadIdx.x;
    for (int i = tid; i < nbk; i += TPB) h[i] = 0;
    __syncthreads();
    int s0 = blockIdx.x * P1_CHUNK;
    int s1 = min(s0 + P1_CHUNK, E);
    for (int i = s0 + tid; i < s1; i += TPB) atomicAdd(&h[col[i] >> DSH], 1);
    __syncthreads();
    for (int i = tid; i < nbk; i += TPB) {
        int c = h[i];
        base[i] = c ? atomicAdd(&ccur[i], c) : 0;
        h[i] = 0;
    }
    __syncthreads();
    for (int i = s0 + tid; i < s1; i += TPB) {
        int c = col[i];
        int b = c >> DSH;
        int r = atomicAdd(&h[b], 1);
        bkt[base[b] + r] = make_int2(row[i] | ((c & (DNB - 1)) << 20), __float_as_int(w[i]));
    }
}

// ---- Pass 2: fine sort within bucket (LDS), write starts + edges coalesced,
//      and compute deg/dinv per dest (its edges are all here).
__global__ __launch_bounds__(TPB) void k_p2(const int2* __restrict__ bkt,
                                            const int* __restrict__ cbase,
                                            int* __restrict__ starts,
                                            int2* __restrict__ edges,
                                            float* __restrict__ dinv, int n, int E) {
    __shared__ int hist[DNB];
    __shared__ int curs[DNB];
    __shared__ int sc[DNB];
    __shared__ int2 stage[STAGE_CAP];
    int tid = threadIdx.x;
    int b = blockIdx.x;
    int s0 = cbase[b], s1 = cbase[b + 1];
    int cnt = s1 - s0;
    int nodeBase = b << DSH;
    if (tid < DNB) hist[tid] = 0;
    __syncthreads();
    for (int i = s0 + tid; i < s1; i += TPB)
        atomicAdd(&hist[(unsigned)bkt[i].x >> 20], 1);
    __syncthreads();
    int v = 0;
    if (tid < DNB) { v = hist[tid]; sc[tid] = v; }
    __syncthreads();
    for (int off = 1; off < DNB; off <<= 1) {
        int t = 0;
        if (tid < DNB && tid >= off) t = sc[tid - off];
        __syncthreads();
        if (tid < DNB) sc[tid] += t;
        __syncthreads();
    }
    if (tid < DNB) {
        int ex = sc[tid] - v;
        curs[tid] = ex;
        int node = nodeBase + tid;
        if (node < n) starts[node] = s0 + ex;
    }
    if (b == 0 && tid == 0) starts[n] = E;
    __syncthreads();
    if (cnt <= STAGE_CAP) {
        for (int i = s0 + tid; i < s1; i += TPB) {
            int2 ed = bkt[i];
            int d = (unsigned)ed.x >> 20;
            int r = atomicAdd(&curs[d], 1);
            stage[r] = make_int2(ed.x & 0xFFFFF, ed.y);
        }
        __syncthreads();
        for (int i = tid; i < cnt; i += TPB) edges[s0 + i] = stage[i];
        // deg/dinv from LDS stage: node tid's run = [sc[tid]-v, sc[tid])
        if (tid < DNB) {
            int node = nodeBase + tid;
            if (node < n) {
                float d = 1.0f;  // self-loop
                for (int j = sc[tid] - v; j < sc[tid]; ++j)
                    d += __int_as_float(stage[j].y);
                dinv[node] = rsqrtf(d);
            }
        }
    } else {  // overflow fallback: direct (uncoalesced but correct)
        for (int i = s0 + tid; i < s1; i += TPB) {
            int2 ed = bkt[i];
            int d = (unsigned)ed.x >> 20;
            int r = atomicAdd(&curs[d], 1);
            edges[s0 + r] = make_int2(ed.x & 0xFFFFF, ed.y);
        }
        __syncthreads();
        if (tid < DNB) {
            int node = nodeBase + tid;
            if (node < n) {
                float d = 1.0f;
                for (int j = sc[tid] - v; j < sc[tid]; ++j)
                    d += __int_as_float(edges[s0 + j].y);
                dinv[node] = rsqrtf(d);
            }
        }
    }
}

// ---- hw'[N,64] (fp16) = dinv[r] * (in[N,64] @ W[64,64]).
// 128 rows/block, 256 threads; thread tile = 8 rows x 4 cols.
// b128 LDS, XOR-swizzled A staging; unroll 2 (full unroll spills);
// launch_bounds(TPB,3) matches the 48KB-LDS occupancy cap.
// Epilogue: scale by dinv[r], convert to fp16.
// cp != nullptr: write staged fp32 input rows through to cp (fuses out0=x memcpy).
__global__ __launch_bounds__(TPB, 3) void k_gemm64(const float* __restrict__ in,
                                                   const float* __restrict__ Wg,
                                                   __half* __restrict__ hwh,
                                                   const float* __restrict__ dinvg,
                                                   float* __restrict__ cp, int n) {
    __shared__ float4 Ws[1024];   // [64 k][16 j4]
    __shared__ float4 As[2048];   // [128 r][16 c4], swizzled
    int tid = threadIdx.x;
    const float4* Wf4 = (const float4*)Wg;
    #pragma unroll
    for (int i = 0; i < 4; ++i) Ws[i * 256 + tid] = Wf4[i * 256 + tid];
    int rowbase = blockIdx.x * 128;
    const float4* Af4 = (const float4*)in;
    #pragma unroll
    for (int i = 0; i < 8; ++i) {
        int f4 = i * 256 + tid;
        int r = f4 >> 4, c4 = f4 & 15;
        float4 v = make_float4(0.f, 0.f, 0.f, 0.f);
        if (rowbase + r < n) {
            v = Af4[(size_t)(rowbase + r) * 16 + c4];
            if (cp) *(float4*)&cp[((size_t)(rowbase + r) * 16 + c4) * 4] = v;
        }
        As[r * 16 + (c4 ^ ((r >> 3) & 3))] = v;
    }
    __syncthreads();
    int jg = tid & 15;       // output col group (4 cols)
    int rg = tid >> 4;       // row group (8 rows)
    int r0 = rg * 8;
    int sw = rg & 3;         // swizzle key for this thread's rows
    float4 acc[8];
    #pragma unroll
    for (int rr = 0; rr < 8; ++rr) acc[rr] = make_float4(0.f, 0.f, 0.f, 0.f);
    #pragma unroll 2
    for (int kt = 0; kt < 16; ++kt) {
        float4 w0 = Ws[(kt * 4 + 0) * 16 + jg];
        float4 w1 = Ws[(kt * 4 + 1) * 16 + jg];
        float4 w2 = Ws[(kt * 4 + 2) * 16 + jg];
        float4 w3 = Ws[(kt * 4 + 3) * 16 + jg];
        int ac = kt ^ sw;
        #pragma unroll
        for (int rr = 0; rr < 8; ++rr) {
            float4 a = As[(r0 + rr) * 16 + ac];
            acc[rr].x = fmaf(a.x, w0.x, acc[rr].x);
            acc[rr].y = fmaf(a.x, w0.y, acc[rr].y);
            acc[rr].z = fmaf(a.x, w0.z, acc[rr].z);
            acc[rr].w = fmaf(a.x, w0.w, acc[rr].w);
            acc[rr].x = fmaf(a.y, w1.x, acc[rr].x);
            acc[rr].y = fmaf(a.y, w1.y, acc[rr].y);
            acc[rr].z = fmaf(a.y, w1.z, acc[rr].z);
            acc[rr].w = fmaf(a.y, w1.w, acc[rr].w);
            acc[rr].x = fmaf(a.z, w2.x, acc[rr].x);
            acc[rr].y = fmaf(a.z, w2.y, acc[rr].y);
            acc[rr].z = fmaf(a.z, w2.z, acc[rr].z);
            acc[rr].w = fmaf(a.z, w2.w, acc[rr].w);
            acc[rr].x = fmaf(a.w, w3.x, acc[rr].x);
            acc[rr].y = fmaf(a.w, w3.y, acc[rr].y);
            acc[rr].z = fmaf(a.w, w3.z, acc[rr].z);
            acc[rr].w = fmaf(a.w, w3.w, acc[rr].w);
        }
    }
    #pragma unroll
    for (int rr = 0; rr < 8; ++rr) {
        int r = rowbase + r0 + rr;
        if (r < n) {
            float di = dinvg[r];
            ushort4 s;
            s.x = __half_as_ushort(__float2half(acc[rr].x * di));
            s.y = __half_as_ushort(__float2half(acc[rr].y * di));
            s.z = __half_as_ushort(__float2half(acc[rr].z * di));
            s.w = __half_as_ushort(__float2half(acc[rr].w * di));
            *(ushort4*)&hwh[(size_t)r * 64 + jg * 4] = s;
        }
    }
}

// ---- gather-aggregate: one wave per node, lane = feature (64 lanes = one 128B
// fp16 row). Edge records are wave-uniform -> scalar loads; row loads are the only
// vector traffic. 8/4/2/1 unroll ladder keeps ~5-6 independent row loads in flight
// (Little's law: the gather is latency-bound, R4 showed bytes don't matter).
// out = dinv[dst]*(hw'[self] + sum w*hw'[src]) + b, hw' has dinv[src] baked in.
__global__ __launch_bounds__(TPB) void k_gather(const int* __restrict__ starts,
                                                const int2* __restrict__ edges,
                                                const __half* __restrict__ hwh,
                                                const float* __restrict__ dinv,
                                                const float* __restrict__ b,
                                                float* __restrict__ out,
                                                int n, int relu) {
    int node = __builtin_amdgcn_readfirstlane(blockIdx.x * (TPB / 64) + (threadIdx.x >> 6));
    if (node >= n) return;
    int lane = threadIdx.x & 63;
    int s0 = starts[node], s1 = starts[node + 1];
    const long long* epk = (const long long*)edges;
    float acc = 0.f;
    int e = s0;
    for (; e + 8 <= s1; e += 8) {
        long long v0 = epk[e + 0];
        long long v1 = epk[e + 1];
        long long v2 = epk[e + 2];
        long long v3 = epk[e + 3];
        long long v4 = epk[e + 4];
        long long v5 = epk[e + 5];
        long long v6 = epk[e + 6];
        long long v7 = epk[e + 7];
        float h0 = __half2float(hwh[(size_t)(int)v0 * 64 + lane]);
        float h1 = __half2float(hwh[(size_t)(int)v1 * 64 + lane]);
        float h2 = __half2float(hwh[(size_t)(int)v2 * 64 + lane]);
        float h3 = __half2float(hwh[(size_t)(int)v3 * 64 + lane]);
        float h4 = __half2float(hwh[(size_t)(int)v4 * 64 + lane]);
        float h5 = __half2float(hwh[(size_t)(int)v5 * 64 + lane]);
        float h6 = __half2float(hwh[(size_t)(int)v6 * 64 + lane]);
        float h7 = __half2float(hwh[(size_t)(int)v7 * 64 + lane]);
        acc = fmaf(h0, __int_as_float((int)(v0 >> 32)), acc);
        acc = fmaf(h1, __int_as_float((int)(v1 >> 32)), acc);
        acc = fmaf(h2, __int_as_float((int)(v2 >> 32)), acc);
        acc = fmaf(h3, __int_as_float((int)(v3 >> 32)), acc);
        acc = fmaf(h4, __int_as_float((int)(v4 >> 32)), acc);
        acc = fmaf(h5, __int_as_float((int)(v5 >> 32)), acc);
        acc = fmaf(h6, __int_as_float((int)(v6 >> 32)), acc);
        acc = fmaf(h7, __int_as_float((int)(v7 >> 32)), acc);
    }
    if (e + 4 <= s1) {
        long long v0 = epk[e + 0];
        long long v1 = epk[e + 1];
        long long v2 = epk[e + 2];
        long long v3 = epk[e + 3];
        float h0 = __half2float(hwh[(size_t)(int)v0 * 64 + lane]);
        float h1 = __half2float(hwh[(size_t)(int)v1 * 64 + lane]);
        float h2 = __half2float(hwh[(size_t)(int)v2 * 64 + lane]);
        float h3 = __half2float(hwh[(size_t)(int)v3 * 64 + lane]);
        acc = fmaf(h0, __int_as_float((int)(v0 >> 32)), acc);
        acc = fmaf(h1, __int_as_float((int)(v1 >> 32)), acc);
        acc = fmaf(h2, __int_as_float((int)(v2 >> 32)), acc);
        acc = fmaf(h3, __int_as_float((int)(v3 >> 32)), acc);
        e += 4;
    }
    if (e + 2 <= s1) {
        long long v0 = epk[e + 0];
        long long v1 = epk[e + 1];
        float h0 = __half2float(hwh[(size_t)(int)v0 * 64 + lane]);
        float h1 = __half2float(hwh[(size_t)(int)v1 * 64 + lane]);
        acc = fmaf(h0, __int_as_float((int)(v0 >> 32)), acc);
        acc = fmaf(h1, __int_as_float((int)(v1 >> 32)), acc);
        e += 2;
    }
    if (e < s1) {
        long long v0 = epk[e];
        float h0 = __half2float(hwh[(size_t)(int)v0 * 64 + lane]);
        acc = fmaf(h0, __int_as_float((int)(v0 >> 32)), acc);
    }
    float di = dinv[node];
    float self = __half2float(hwh[(size_t)node * 64 + lane]);
    float o = fmaf(self + acc, di, b[lane]);
    if (relu) o = o > 0.f ? o : 0.f;
    out[(size_t)node * 64 + lane] = o;
}

extern "C" void kernel_launch(void* const* d_in, const int* in_sizes, int n_in,
                              void* d_out, int out_size, void* d_ws, size_t ws_size,
                              hipStream_t stream) {
    const float* x = (const float*)d_in[0];
    const int* ei = (const int*)d_in[1];      // int32 on device
    const float* ew = (const float*)d_in[2];
    const float* Wl[3] = {(const float*)d_in[3], (const float*)d_in[5], (const float*)d_in[7]};
    const float* Bl[3] = {(const float*)d_in[4], (const float*)d_in[6], (const float*)d_in[8]};

    const int n = in_sizes[0] / 64;
    const int E = in_sizes[2];
    const int* row = ei;       // edge_index[0]
    const int* col = ei + E;   // edge_index[1]
    float* out = (float*)d_out;

    const int nbk = (n + DNB - 1) >> DSH;                 // coarse buckets (<=1024 for n<=131072)
    const int p1b = (E + P1_CHUNK - 1) / P1_CHUNK;

    // workspace layout (256B aligned):
    // dinv[n] | hwh fp16[n*64] (bkt int2[E] aliased; hwh written only after pass 2)
    // | starts[n+1] | chist[1024] | cbase[1025] | ccur[1024] | edges[E] int2
    char* ws = (char*)d_ws;
    size_t o = 0;
    float* dinv  = (float*)(ws + o);  o = (o + (size_t)n * 4 + 255) & ~(size_t)255;
    __half* hwh  = (__half*)(ws + o);
    int2*  bkt   = (int2*)(ws + o);
    {
        size_t hb = (size_t)n * 128, bb = (size_t)E * 8;
        o = (o + (hb > bb ? hb : bb) + 255) & ~(size_t)255;
    }
    int* starts  = (int*)(ws + o);    o = (o + (size_t)(n + 1) * 4 + 255) & ~(size_t)255;
    int* chist   = (int*)(ws + o);    o = (o + 1024 * 4 + 255) & ~(size_t)255;
    int* cbase   = (int*)(ws + o);    o = (o + 1025 * 4 + 255) & ~(size_t)255;
    int* ccur    = (int*)(ws + o);    o = (o + 1024 * 4 + 255) & ~(size_t)255;
    int2* edges  = (int2*)(ws + o);

    // CSR by destination: 2-level counting sort (+ fused deg/dinv in pass 2)
    hipMemsetAsync(chist, 0, (size_t)nbk * 4, stream);
    k_p0<<<p1b, TPB, 0, stream>>>(col, chist, E, nbk);
    k_scanb<<<1, 1024, 0, stream>>>(chist, cbase, ccur, nbk, E);
    k_p1<<<p1b, TPB, 0, stream>>>(row, col, ew, ccur, bkt, E, nbk);
    k_p2<<<nbk, TPB, 0, stream>>>(bkt, cbase, starts, edges, dinv, n, E);
    // norm folded into gather; dinv[src] baked into hwh by gemm epilogue

    const float* hin = x;
    for (int L = 0; L < 3; ++L) {
        float* oseg = out + (size_t)(L + 1) * n * 64;
        // L==0: write-through x -> out segment 0 (replaces memcpy)
        k_gemm64<<<(n + 127) / 128, TPB, 0, stream>>>(hin, Wl[L], hwh, dinv, L == 0 ? out : nullptr, n);
        k_gather<<<(n * 64 + TPB - 1) / TPB, TPB, 0, stream>>>(starts, edges, hwh, dinv, Bl[L], oseg, n, L < 2 ? 1 : 0);
        hin = oseg;
    }
}

// Round 6
// 359.749 us; speedup vs baseline: 1.9931x; 1.0253x over previous
//
#include <hip/hip_runtime.h>
#include <hip/hip_fp16.h>

// GCN: 3x (h@W -> gather-aggregate via CSR-by-dest + self-loop + bias [-> ReLU])
// Outputs: concat(x, h1, h2, h3), each [N,64] fp32.
// CSR via 2-level counting sort; deg/dinv fused into pass 2.
// R2: vector gemm, unroll 2 + launch_bounds cap (28us/layer).
// R3: normcsr deleted (norm factored into gather); memcpy fused into gemm L0.
// R4: hw stored fp16, dinv baked -> gather latency-bound diagnosis.
// R5: gather wave-per-node, lane=feature, scalar edge loads, 8/4/2/1 ladder (-55us).
// R6: k_gemm64 -> MFMA (mfma_f32_16x16x32_f16). 128 rows/block, 4 waves, each wave
//     2x4 16x16 tiles x 2 K-steps. A pre-scaled by dinv[row] at staging (row scaling
//     commutes with @W). WT[n][k] in LDS for contiguous B-frags. Chunk-XOR swizzle
//     (c4 ^= r&7) on As/Bs/bounce. Epilogue: acc -> LDS fp16 bounce -> b128 stores.
//     Per-wave LDS reads 192 b128/thread -> 12 b128/wave.

#define TPB 256
#define P1_CHUNK 4096   // edges per block in pass0/pass1
#define DSH 7           // coarse bucket = dest >> DSH (128 dests/bucket)
#define DNB 128         // dests per bucket
#define STAGE_CAP 4096  // pass-2 LDS staging capacity (edges)

typedef _Float16 half8 __attribute__((ext_vector_type(8)));
typedef float f32x4 __attribute__((ext_vector_type(4)));

// ---- Pass 0: coarse histogram (per-block LDS hist, merged with few global atomics)
__global__ __launch_bounds__(TPB) void k_p0(const int* __restrict__ col,
                                            int* __restrict__ chist, int E, int nbk) {
    __shared__ int h[1024];
    int tid = threadIdx.x;
    for (int i = tid; i < nbk; i += TPB) h[i] = 0;
    __syncthreads();
    int s0 = blockIdx.x * P1_CHUNK;
    int s1 = min(s0 + P1_CHUNK, E);
    for (int i = s0 + tid; i < s1; i += TPB) atomicAdd(&h[col[i] >> DSH], 1);
    __syncthreads();
    for (int i = tid; i < nbk; i += TPB)
        if (h[i]) atomicAdd(&chist[i], h[i]);
}

// ---- Scan coarse buckets (single block), init cursor copy.
__global__ __launch_bounds__(1024) void k_scanb(const int* __restrict__ chist,
                                                int* __restrict__ cbase,
                                                int* __restrict__ ccur, int nbk, int E) {
    __shared__ int s[1024];
    int tid = threadIdx.x;
    int v = (tid < nbk) ? chist[tid] : 0;
    s[tid] = v;
    __syncthreads();
    for (int off = 1; off < 1024; off <<= 1) {
        int t = (tid >= off) ? s[tid - off] : 0;
        __syncthreads();
        s[tid] += t;
        __syncthreads();
    }
    if (tid < nbk) { int ex = s[tid] - v; cbase[tid] = ex; ccur[tid] = ex; }
    if (tid == 0) cbase[nbk] = E;
}

// ---- Pass 1: scatter edges into coarse-bucket runs (one global atomic per block-bucket).
// Packs (src | destlo<<20, w) so pass 2 doesn't need col[].
__global__ __launch_bounds__(TPB) void k_p1(const int* __restrict__ row,
                                            const int* __restrict__ col,
                                            const float* __restrict__ w,
                                            int* __restrict__ ccur,
                                            int2* __restrict__ bkt, int E, int nbk) {
    __shared__ int h[1024];
    __shared__ int base[1024];
    int tid = threadIdx.x;
    for (int i = tid; i < nbk; i += TPB) h[i] = 0;
    __syncthreads();
    int s0 = blockIdx.x * P1_CHUNK;
    int s1 = min(s0 + P1_CHUNK, E);
    for (int i = s0 + tid; i < s1; i += TPB) atomicAdd(&h[col[i] >> DSH], 1);
    __syncthreads();
    for (int i = tid; i < nbk; i += TPB) {
        int c = h[i];
        base[i] = c ? atomicAdd(&ccur[i], c) : 0;
        h[i] = 0;
    }
    __syncthreads();
    for (int i = s0 + tid; i < s1; i += TPB) {
        int c = col[i];
        int b = c >> DSH;
        int r = atomicAdd(&h[b], 1);
        bkt[base[b] + r] = make_int2(row[i] | ((c & (DNB - 1)) << 20), __float_as_int(w[i]));
    }
}

// ---- Pass 2: fine sort within bucket (LDS), write starts + edges coalesced,
//      and compute deg/dinv per dest (its edges are all here).
__global__ __launch_bounds__(TPB) void k_p2(const int2* __restrict__ bkt,
                                            const int* __restrict__ cbase,
                                            int* __restrict__ starts,
                                            int2* __restrict__ edges,
                                            float* __restrict__ dinv, int n, int E) {
    __shared__ int hist[DNB];
    __shared__ int curs[DNB];
    __shared__ int sc[DNB];
    __shared__ int2 stage[STAGE_CAP];
    int tid = threadIdx.x;
    int b = blockIdx.x;
    int s0 = cbase[b], s1 = cbase[b + 1];
    int cnt = s1 - s0;
    int nodeBase = b << DSH;
    if (tid < DNB) hist[tid] = 0;
    __syncthreads();
    for (int i = s0 + tid; i < s1; i += TPB)
        atomicAdd(&hist[(unsigned)bkt[i].x >> 20], 1);
    __syncthreads();
    int v = 0;
    if (tid < DNB) { v = hist[tid]; sc[tid] = v; }
    __syncthreads();
    for (int off = 1; off < DNB; off <<= 1) {
        int t = 0;
        if (tid < DNB && tid >= off) t = sc[tid - off];
        __syncthreads();
        if (tid < DNB) sc[tid] += t;
        __syncthreads();
    }
    if (tid < DNB) {
        int ex = sc[tid] - v;
        curs[tid] = ex;
        int node = nodeBase + tid;
        if (node < n) starts[node] = s0 + ex;
    }
    if (b == 0 && tid == 0) starts[n] = E;
    __syncthreads();
    if (cnt <= STAGE_CAP) {
        for (int i = s0 + tid; i < s1; i += TPB) {
            int2 ed = bkt[i];
            int d = (unsigned)ed.x >> 20;
            int r = atomicAdd(&curs[d], 1);
            stage[r] = make_int2(ed.x & 0xFFFFF, ed.y);
        }
        __syncthreads();
        for (int i = tid; i < cnt; i += TPB) edges[s0 + i] = stage[i];
        // deg/dinv from LDS stage: node tid's run = [sc[tid]-v, sc[tid])
        if (tid < DNB) {
            int node = nodeBase + tid;
            if (node < n) {
                float d = 1.0f;  // self-loop
                for (int j = sc[tid] - v; j < sc[tid]; ++j)
                    d += __int_as_float(stage[j].y);
                dinv[node] = rsqrtf(d);
            }
        }
    } else {  // overflow fallback: direct (uncoalesced but correct)
        for (int i = s0 + tid; i < s1; i += TPB) {
            int2 ed = bkt[i];
            int d = (unsigned)ed.x >> 20;
            int r = atomicAdd(&curs[d], 1);
            edges[s0 + r] = make_int2(ed.x & 0xFFFFF, ed.y);
        }
        __syncthreads();
        if (tid < DNB) {
            int node = nodeBase + tid;
            if (node < n) {
                float d = 1.0f;
                for (int j = sc[tid] - v; j < sc[tid]; ++j)
                    d += __int_as_float(edges[s0 + j].y);
                dinv[node] = rsqrtf(d);
            }
        }
    }
}

// ---- hw'[N,64] (fp16) = dinv[r] * (in[N,64] @ W[64,64])  via MFMA.
// Block: 128 rows, 256 threads = 4 waves; wave w owns rows w*32..w*32+31.
// Per wave: 2 m-tiles x 4 n-tiles of mfma_f32_16x16x32_f16, 2 K-steps.
// Fragment map (m89-verified family): A lane holds A[lane%16][8*(lane/16)+i];
// B lane holds B[8*(lane/16)+i][lane%16] -> stage W transposed (WT[n][k]) for
// contiguous b128 reads. C/D: col=lane&15, row=4*(lane>>4)+reg.
// dinv[r] folded into A staging (row scaling commutes with @W).
// All LDS tiles chunk-XOR swizzled: 8-half chunk c4 stored at c4^(r&7).
// cp != nullptr: write staged fp32 rows through to cp (fuses out0=x memcpy).
__global__ __launch_bounds__(TPB, 4) void k_gemm64(const float* __restrict__ in,
                                                   const float* __restrict__ Wg,
                                                   __half* __restrict__ hwh,
                                                   const float* __restrict__ dinvg,
                                                   float* __restrict__ cp, int n) {
    __shared__ _Float16 As[128 * 64];   // 16 KB, swizzled; reused as epilogue bounce
    __shared__ _Float16 Bs[64 * 64];    // 8 KB, WT[n][k], swizzled
    int tid = threadIdx.x;
    int rowbase = blockIdx.x * 128;

    // ---- stage W -> Bs (transposed, fp16, swizzled)
    {
        const float4* W4 = (const float4*)Wg;
        #pragma unroll
        for (int it = 0; it < 4; ++it) {
            int k = (tid >> 4) + 16 * it;        // 0..63
            int n0 = (tid & 15) * 4;             // 0..60
            float4 wv = W4[k * 16 + (tid & 15)]; // W[k][n0..n0+3]
            #pragma unroll
            for (int j = 0; j < 4; ++j) {
                int nn = n0 + j;
                float e = (j == 0) ? wv.x : (j == 1) ? wv.y : (j == 2) ? wv.z : wv.w;
                Bs[nn * 64 + (((k >> 3) ^ (nn & 7)) << 3) + (k & 7)] = (_Float16)e;
            }
        }
    }
    // ---- stage A rows -> As (fp16, scaled by dinv[r], swizzled); write-through cp
    {
        int r = tid >> 1;                 // local row 0..127
        int gr = rowbase + r;
        int c0 = (tid & 1) * 32;          // half of the row (32 halves)
        float di = (gr < n) ? dinvg[gr] : 0.f;
        const float4* A4 = (const float4*)in;
        #pragma unroll
        for (int j = 0; j < 4; ++j) {     // 4 chunks of 8 halves
            float4 v0 = make_float4(0.f, 0.f, 0.f, 0.f);
            float4 v1 = v0;
            if (gr < n) {
                v0 = A4[(size_t)gr * 16 + (c0 >> 2) + j * 2];
                v1 = A4[(size_t)gr * 16 + (c0 >> 2) + j * 2 + 1];
                if (cp) {
                    *(float4*)&cp[((size_t)gr * 16 + (c0 >> 2) + j * 2) * 4] = v0;
                    *(float4*)&cp[((size_t)gr * 16 + (c0 >> 2) + j * 2 + 1) * 4] = v1;
                }
            }
            int c4 = (c0 >> 3) + j;
            half8 hv;
            hv[0] = (_Float16)(v0.x * di); hv[1] = (_Float16)(v0.y * di);
            hv[2] = (_Float16)(v0.z * di); hv[3] = (_Float16)(v0.w * di);
            hv[4] = (_Float16)(v1.x * di); hv[5] = (_Float16)(v1.y * di);
            hv[6] = (_Float16)(v1.z * di); hv[7] = (_Float16)(v1.w * di);
            *(half8*)&As[r * 64 + ((c4 ^ (r & 7)) << 3)] = hv;
        }
    }
    __syncthreads();

    // ---- MFMA compute
    int w = tid >> 6;
    int lane = tid & 63;
    int l15 = lane & 15, l4 = lane >> 4;
    f32x4 acc[2][4];
    #pragma unroll
    for (int mt = 0; mt < 2; ++mt)
        #pragma unroll
        for (int nt = 0; nt < 4; ++nt) acc[mt][nt] = (f32x4){0.f, 0.f, 0.f, 0.f};
    const half8* Av = (const half8*)As;
    const half8* Bv = (const half8*)Bs;
    #pragma unroll
    for (int kk = 0; kk < 2; ++kk) {
        int ck = kk * 4 + l4;
        half8 a0 = Av[(w * 32 + l15) * 8 + (ck ^ (l15 & 7))];
        half8 a1 = Av[(w * 32 + 16 + l15) * 8 + (ck ^ (l15 & 7))];
        #pragma unroll
        for (int nt = 0; nt < 4; ++nt) {
            half8 b = Bv[(nt * 16 + l15) * 8 + (ck ^ (l15 & 7))];
            acc[0][nt] = __builtin_amdgcn_mfma_f32_16x16x32_f16(a0, b, acc[0][nt], 0, 0, 0);
            acc[1][nt] = __builtin_amdgcn_mfma_f32_16x16x32_f16(a1, b, acc[1][nt], 0, 0, 0);
        }
    }
    __syncthreads();   // done reading As/Bs everywhere

    // ---- epilogue: acc -> fp16 bounce in As (swizzled) -> coalesced b128 stores
    #pragma unroll
    for (int mt = 0; mt < 2; ++mt)
        #pragma unroll
        for (int nt = 0; nt < 4; ++nt)
            #pragma unroll
            for (int rg = 0; rg < 4; ++rg) {
                int r = w * 32 + mt * 16 + l4 * 4 + rg;
                int c = nt * 16 + l15;
                As[r * 64 + (((c >> 3) ^ (r & 7)) << 3) + (c & 7)] =
                    (_Float16)acc[mt][nt][rg];
            }
    __syncthreads();
    #pragma unroll
    for (int it = 0; it < 4; ++it) {
        int idx = it * 256 + tid;     // chunk id 0..1023
        int r = idx >> 3, c4 = idx & 7;
        int gr = rowbase + r;
        if (gr < n) {
            half8 hv = *(const half8*)&As[r * 64 + ((c4 ^ (r & 7)) << 3)];
            *(half8*)&hwh[(size_t)gr * 64 + c4 * 8] = hv;
        }
    }
}

// ---- gather-aggregate: one wave per node, lane = feature (64 lanes = one 128B
// fp16 row). Edge records are wave-uniform -> scalar loads; row loads are the only
// vector traffic. 8/4/2/1 unroll ladder keeps ~5-6 independent row loads in flight
// (Little's law: the gather is latency-bound, R4 showed bytes don't matter).
// out = dinv[dst]*(hw'[self] + sum w*hw'[src]) + b, hw' has dinv[src] baked in.
__global__ __launch_bounds__(TPB) void k_gather(const int* __restrict__ starts,
                                                const int2* __restrict__ edges,
                                                const __half* __restrict__ hwh,
                                                const float* __restrict__ dinv,
                                                const float* __restrict__ b,
                                                float* __restrict__ out,
                                                int n, int relu) {
    int node = __builtin_amdgcn_readfirstlane(blockIdx.x * (TPB / 64) + (threadIdx.x >> 6));
    if (node >= n) return;
    int lane = threadIdx.x & 63;
    int s0 = starts[node], s1 = starts[node + 1];
    const long long* epk = (const long long*)edges;
    float acc = 0.f;
    int e = s0;
    for (; e + 8 <= s1; e += 8) {
        long long v0 = epk[e + 0];
        long long v1 = epk[e + 1];
        long long v2 = epk[e + 2];
        long long v3 = epk[e + 3];
        long long v4 = epk[e + 4];
        long long v5 = epk[e + 5];
        long long v6 = epk[e + 6];
        long long v7 = epk[e + 7];
        float h0 = __half2float(hwh[(size_t)(int)v0 * 64 + lane]);
        float h1 = __half2float(hwh[(size_t)(int)v1 * 64 + lane]);
        float h2 = __half2float(hwh[(size_t)(int)v2 * 64 + lane]);
        float h3 = __half2float(hwh[(size_t)(int)v3 * 64 + lane]);
        float h4 = __half2float(hwh[(size_t)(int)v4 * 64 + lane]);
        float h5 = __half2float(hwh[(size_t)(int)v5 * 64 + lane]);
        float h6 = __half2float(hwh[(size_t)(int)v6 * 64 + lane]);
        float h7 = __half2float(hwh[(size_t)(int)v7 * 64 + lane]);
        acc = fmaf(h0, __int_as_float((int)(v0 >> 32)), acc);
        acc = fmaf(h1, __int_as_float((int)(v1 >> 32)), acc);
        acc = fmaf(h2, __int_as_float((int)(v2 >> 32)), acc);
        acc = fmaf(h3, __int_as_float((int)(v3 >> 32)), acc);
        acc = fmaf(h4, __int_as_float((int)(v4 >> 32)), acc);
        acc = fmaf(h5, __int_as_float((int)(v5 >> 32)), acc);
        acc = fmaf(h6, __int_as_float((int)(v6 >> 32)), acc);
        acc = fmaf(h7, __int_as_float((int)(v7 >> 32)), acc);
    }
    if (e + 4 <= s1) {
        long long v0 = epk[e + 0];
        long long v1 = epk[e + 1];
        long long v2 = epk[e + 2];
        long long v3 = epk[e + 3];
        float h0 = __half2float(hwh[(size_t)(int)v0 * 64 + lane]);
        float h1 = __half2float(hwh[(size_t)(int)v1 * 64 + lane]);
        float h2 = __half2float(hwh[(size_t)(int)v2 * 64 + lane]);
        float h3 = __half2float(hwh[(size_t)(int)v3 * 64 + lane]);
        acc = fmaf(h0, __int_as_float((int)(v0 >> 32)), acc);
        acc = fmaf(h1, __int_as_float((int)(v1 >> 32)), acc);
        acc = fmaf(h2, __int_as_float((int)(v2 >> 32)), acc);
        acc = fmaf(h3, __int_as_float((int)(v3 >> 32)), acc);
        e += 4;
    }
    if (e + 2 <= s1) {
        long long v0 = epk[e + 0];
        long long v1 = epk[e + 1];
        float h0 = __half2float(hwh[(size_t)(int)v0 * 64 + lane]);
        float h1 = __half2float(hwh[(size_t)(int)v1 * 64 + lane]);
        acc = fmaf(h0, __int_as_float((int)(v0 >> 32)), acc);
        acc = fmaf(h1, __int_as_float((int)(v1 >> 32)), acc);
        e += 2;
    }
    if (e < s1) {
        long long v0 = epk[e];
        float h0 = __half2float(hwh[(size_t)(int)v0 * 64 + lane]);
        acc = fmaf(h0, __int_as_float((int)(v0 >> 32)), acc);
    }
    float di = dinv[node];
    float self = __half2float(hwh[(size_t)node * 64 + lane]);
    float o = fmaf(self + acc, di, b[lane]);
    if (relu) o = o > 0.f ? o : 0.f;
    out[(size_t)node * 64 + lane] = o;
}

extern "C" void kernel_launch(void* const* d_in, const int* in_sizes, int n_in,
                              void* d_out, int out_size, void* d_ws, size_t ws_size,
                              hipStream_t stream) {
    const float* x = (const float*)d_in[0];
    const int* ei = (const int*)d_in[1];      // int32 on device
    const float* ew = (const float*)d_in[2];
    const float* Wl[3] = {(const float*)d_in[3], (const float*)d_in[5], (const float*)d_in[7]};
    const float* Bl[3] = {(const float*)d_in[4], (const float*)d_in[6], (const float*)d_in[8]};

    const int n = in_sizes[0] / 64;
    const int E = in_sizes[2];
    const int* row = ei;       // edge_index[0]
    const int* col = ei + E;   // edge_index[1]
    float* out = (float*)d_out;

    const int nbk = (n + DNB - 1) >> DSH;                 // coarse buckets (<=1024 for n<=131072)
    const int p1b = (E + P1_CHUNK - 1) / P1_CHUNK;

    // workspace layout (256B aligned):
    // dinv[n] | hwh fp16[n*64] (bkt int2[E] aliased; hwh written only after pass 2)
    // | starts[n+1] | chist[1024] | cbase[1025] | ccur[1024] | edges[E] int2
    char* ws = (char*)d_ws;
    size_t o = 0;
    float* dinv  = (float*)(ws + o);  o = (o + (size_t)n * 4 + 255) & ~(size_t)255;
    __half* hwh  = (__half*)(ws + o);
    int2*  bkt   = (int2*)(ws + o);
    {
        size_t hb = (size_t)n * 128, bb = (size_t)E * 8;
        o = (o + (hb > bb ? hb : bb) + 255) & ~(size_t)255;
    }
    int* starts  = (int*)(ws + o);    o = (o + (size_t)(n + 1) * 4 + 255) & ~(size_t)255;
    int* chist   = (int*)(ws + o);    o = (o + 1024 * 4 + 255) & ~(size_t)255;
    int* cbase   = (int*)(ws + o);    o = (o + 1025 * 4 + 255) & ~(size_t)255;
    int* ccur    = (int*)(ws + o);    o = (o + 1024 * 4 + 255) & ~(size_t)255;
    int2* edges  = (int2*)(ws + o);

    // CSR by destination: 2-level counting sort (+ fused deg/dinv in pass 2)
    hipMemsetAsync(chist, 0, (size_t)nbk * 4, stream);
    k_p0<<<p1b, TPB, 0, stream>>>(col, chist, E, nbk);
    k_scanb<<<1, 1024, 0, stream>>>(chist, cbase, ccur, nbk, E);
    k_p1<<<p1b, TPB, 0, stream>>>(row, col, ew, ccur, bkt, E, nbk);
    k_p2<<<nbk, TPB, 0, stream>>>(bkt, cbase, starts, edges, dinv, n, E);
    // norm folded into gather; dinv[src] baked into hwh by gemm A-staging

    const float* hin = x;
    for (int L = 0; L < 3; ++L) {
        float* oseg = out + (size_t)(L + 1) * n * 64;
        // L==0: write-through x -> out segment 0 (replaces memcpy)
        k_gemm64<<<(n + 127) / 128, TPB, 0, stream>>>(hin, Wl[L], hwh, dinv, L == 0 ? out : nullptr, n);
        k_gather<<<(n * 64 + TPB - 1) / TPB, TPB, 0, stream>>>(starts, edges, hwh, dinv, Bl[L], oseg, n, L < 2 ? 1 : 0);
        hin = oseg;
    }
}